// Round 1
// baseline (1781.285 us; speedup 1.0000x reference)
//
#include <hip/hip_runtime.h>
#include <hip/hip_bf16.h>
#include <math.h>

#define N_NODES 50000
#define N_EDGES 800000
#define N_GRAPH 128
#define F_IN    1024
#define D_HID   128

typedef __bf16 bf16x8 __attribute__((ext_vector_type(8)));
typedef float  f32x4  __attribute__((ext_vector_type(4)));

__device__ __forceinline__ float lrelu01(float x){ return x > 0.f ? x : 0.01f*x; }
__device__ __forceinline__ float lrelu02(float x){ return x > 0.f ? x : 0.2f*x; }
__device__ __forceinline__ ushort f2bf(float v){
    __hip_bfloat16 hb = __float2bfloat16(v);
    return *reinterpret_cast<ushort*>(&hb);
}

// ---------- W [1024][128] f32 -> Wt [128][1024] bf16 ----------
__global__ void k_cast_wt(const float* __restrict__ W, ushort* __restrict__ Wt){
    int t = blockIdx.x*256 + threadIdx.x;          // 128*1024 elements
    int n = t >> 10, k = t & 1023;
    Wt[t] = f2bf(W[k*D_HID + n]);
}

// ---------- GEMM: h[M][128] = x[M][1024] @ W, bf16 MFMA 16x16x32 ----------
#define BM  128
#define BK  64
#define LDP 72   // padded LDS row stride (elements)

__global__ __launch_bounds__(256) void k_gemm(const float* __restrict__ X,
                                              const ushort* __restrict__ Wt,
                                              float* __restrict__ H, int M){
    __shared__ ushort As[BM*LDP];
    __shared__ ushort Bs[D_HID*LDP];
    int tid  = threadIdx.x;
    int m0   = blockIdx.x * BM;
    int lane = tid & 63;
    int wave = tid >> 6;
    int wr = wave >> 1, wc = wave & 1;
    int l15 = lane & 15, l4 = lane >> 4;

    f32x4 acc[4][4];
    for (int i=0;i<4;i++) for (int j=0;j<4;j++) acc[i][j] = (f32x4){0.f,0.f,0.f,0.f};

    for (int kt = 0; kt < F_IN; kt += BK) {
        // stage A: 128x64 f32 -> bf16 (2048 float4 units, 8 per thread)
        #pragma unroll
        for (int i=0;i<8;i++){
            int q   = tid + i*256;
            int row = q >> 4;
            int kq  = (q & 15) << 2;
            int gr  = m0 + row;
            float4 v = make_float4(0.f,0.f,0.f,0.f);
            if (gr < M) v = *reinterpret_cast<const float4*>(X + (size_t)gr*F_IN + kt + kq);
            ushort4 b; b.x=f2bf(v.x); b.y=f2bf(v.y); b.z=f2bf(v.z); b.w=f2bf(v.w);
            *reinterpret_cast<ushort4*>(&As[row*LDP + kq]) = b;
        }
        // stage B: Wt rows (bf16), 128x64, 16B units (1024 units, 4 per thread)
        #pragma unroll
        for (int i=0;i<4;i++){
            int q   = tid + i*256;
            int row = q >> 3;
            int kq  = (q & 7) << 3;
            *reinterpret_cast<uint4*>(&Bs[row*LDP + kq]) =
                *reinterpret_cast<const uint4*>(Wt + row*F_IN + kt + kq);
        }
        __syncthreads();
        #pragma unroll
        for (int kk = 0; kk < BK; kk += 32) {
            bf16x8 af[4], bfr[4];
            #pragma unroll
            for (int mi=0;mi<4;mi++)
                af[mi] = *reinterpret_cast<const bf16x8*>(&As[(wr*64+mi*16+l15)*LDP + kk + l4*8]);
            #pragma unroll
            for (int ni=0;ni<4;ni++)
                bfr[ni] = *reinterpret_cast<const bf16x8*>(&Bs[(wc*64+ni*16+l15)*LDP + kk + l4*8]);
            #pragma unroll
            for (int mi=0;mi<4;mi++)
                #pragma unroll
                for (int ni=0;ni<4;ni++)
                    acc[mi][ni] = __builtin_amdgcn_mfma_f32_16x16x32_bf16(af[mi], bfr[ni], acc[mi][ni], 0,0,0);
        }
        __syncthreads();
    }
    #pragma unroll
    for (int mi=0;mi<4;mi++){
        #pragma unroll
        for (int jj=0;jj<4;jj++){
            int r = m0 + wr*64 + mi*16 + l4*4 + jj;
            if (r < M){
                #pragma unroll
                for (int ni=0;ni<4;ni++){
                    int c = wc*64 + ni*16 + l15;
                    H[(size_t)r*D_HID + c] = acc[mi][ni][jj];
                }
            }
        }
    }
}

// ---------- al_s/al_d = h @ a_src / h @ a_dst (one wave per row) ----------
__global__ __launch_bounds__(256) void k_al(const float* __restrict__ H,
                    const float* __restrict__ asrc, const float* __restrict__ adst,
                    float* __restrict__ als, float* __restrict__ ald){
    int lane = threadIdx.x & 63;
    int row  = blockIdx.x*4 + (threadIdx.x >> 6);
    if (row >= N_NODES) return;
    float2 v  = *reinterpret_cast<const float2*>(H + (size_t)row*D_HID + 2*lane);
    float2 as = *reinterpret_cast<const float2*>(asrc + 2*lane);
    float2 ad = *reinterpret_cast<const float2*>(adst + 2*lane);
    float ds = v.x*as.x + v.y*as.y;
    float dd = v.x*ad.x + v.y*ad.y;
    for (int o=32;o;o>>=1){ ds += __shfl_xor(ds,o); dd += __shfl_xor(dd,o); }
    if (lane==0){ als[row]=ds; ald[row]=dd; }
}

// ---------- CSR build ----------
__global__ void k_zero(int* __restrict__ p, int n){
    int i = blockIdx.x*256 + threadIdx.x;
    if (i < n) p[i] = 0;
}
__global__ void k_count(const int* __restrict__ dst, int* __restrict__ deg){
    int e = blockIdx.x*256 + threadIdx.x;
    if (e < N_EDGES) atomicAdd(&deg[dst[e]], 1);
}
#define SCAN_CH 49
__global__ __launch_bounds__(1024) void k_scan(const int* __restrict__ deg,
                                               int* __restrict__ off, int* __restrict__ cur){
    __shared__ int s[1024];
    int t = threadIdx.x;
    int base = t*SCAN_CH;
    int loc[SCAN_CH];
    int sum = 0;
    #pragma unroll
    for (int i=0;i<SCAN_CH;i++){
        int idx = base+i;
        int v = (idx < N_NODES) ? deg[idx] : 0;
        loc[i]=v; sum+=v;
    }
    s[t]=sum; __syncthreads();
    for (int o=1;o<1024;o<<=1){
        int v = (t>=o) ? s[t-o] : 0;
        __syncthreads();
        s[t]+=v;
        __syncthreads();
    }
    int run = s[t]-sum;    // exclusive
    #pragma unroll
    for (int i=0;i<SCAN_CH;i++){
        int idx = base+i;
        if (idx < N_NODES){ off[idx]=run; cur[idx]=run; run+=loc[i]; }
    }
    if (t==1023) off[N_NODES] = s[1023];
}
__global__ void k_fill(const int* __restrict__ src, const int* __restrict__ dst,
                       int* __restrict__ cur, int* __restrict__ esrc){
    int e = blockIdx.x*256 + threadIdx.x;
    if (e < N_EDGES){
        int p = atomicAdd(&cur[dst[e]], 1);
        esrc[p] = src[e];
    }
}

// ---------- per-dst GAT aggregate (one wave per dst, self-loop inline) ----------
__global__ __launch_bounds__(256) void k_gat(const int* __restrict__ off, const int* __restrict__ esrc,
                     const float* __restrict__ als, const float* __restrict__ ald,
                     const float* __restrict__ H, const float* __restrict__ bvec,
                     float* __restrict__ hacc, int first){
    int lane = threadIdx.x & 63;
    int d = blockIdx.x*4 + (threadIdx.x >> 6);
    if (d >= N_NODES) return;
    int s0 = off[d], s1 = off[d+1];
    int deg = s1 - s0;
    float aldd  = ald[d];
    float eself = lrelu02(als[d] + aldd);
    // pass 1: max logit
    float mx = eself;
    for (int base=0; base<deg; base+=64){
        int j = base + lane;
        float e = -1e30f;
        if (j < deg){ int s = esrc[s0+j]; e = lrelu02(als[s] + aldd); }
        mx = fmaxf(mx, e);
    }
    for (int o=32;o;o>>=1) mx = fmaxf(mx, __shfl_xor(mx,o));
    // pass 2: exp-sum + weighted h accumulate
    float2 acc = {0.f, 0.f};
    float dsum = 0.f;
    for (int base=0; base<deg; base+=64){
        int j = base + lane;
        int s = d; float ex = 0.f;
        if (j < deg){ s = esrc[s0+j]; ex = expf(lrelu02(als[s] + aldd) - mx); }
        dsum += ex;
        int cnt = min(64, deg - base);
        for (int jj=0; jj<cnt; jj++){
            int   sj  = __shfl(s,  jj);
            float exj = __shfl(ex, jj);
            float2 hv = *reinterpret_cast<const float2*>(H + (size_t)sj*D_HID + 2*lane);
            acc.x += exj*hv.x; acc.y += exj*hv.y;
        }
    }
    for (int o=32;o;o>>=1) dsum += __shfl_xor(dsum,o);
    float exs = expf(eself - mx);
    float2 hv = *reinterpret_cast<const float2*>(H + (size_t)d*D_HID + 2*lane);
    acc.x += exs*hv.x; acc.y += exs*hv.y;
    float denom = dsum + exs;
    float2 bv = *reinterpret_cast<const float2*>(bvec + 2*lane);
    float o0 = lrelu01(acc.x/denom + bv.x);
    float o1 = lrelu01(acc.y/denom + bv.y);
    float2* hp = reinterpret_cast<float2*>(hacc + (size_t)d*D_HID + 2*lane);
    if (first){ *hp = make_float2(o0, o1); }
    else { float2 old = *hp; *hp = make_float2(old.x+o0, old.y+o1); }
}

// ---------- mean-pool per graph + branch FC (one block per graph) ----------
__global__ __launch_bounds__(256) void k_pool_fc(const float* __restrict__ hacc,
                    const int* __restrict__ batch,
                    const float* __restrict__ fcW, const float* __restrict__ fcb,
                    float* __restrict__ xb){
    __shared__ float sums[2][128];
    __shared__ float pl[128];
    int g = blockIdx.x;
    int t = threadIdx.x;
    int lo=0, hi=N_NODES;
    while (lo<hi){ int mid=(lo+hi)>>1; if (batch[mid] < g) lo=mid+1; else hi=mid; }
    int s = lo;
    lo = s; hi = N_NODES;
    while (lo<hi){ int mid=(lo+hi)>>1; if (batch[mid] < g+1) lo=mid+1; else hi=mid; }
    int e = lo;
    int f = t & 127, half = t >> 7;
    float sum = 0.f;
    for (int n=s+half; n<e; n+=2) sum += hacc[(size_t)n*D_HID + f];
    sums[half][f] = sum;
    __syncthreads();
    if (t < 128){
        float cnt = (float)(e - s);
        pl[t] = (sums[0][t] + sums[1][t]) / fmaxf(cnt, 1.0f);
    }
    __syncthreads();
    if (t < 128){
        float a = fcb[t];
        for (int k=0;k<128;k++) a += pl[k]*fcW[k*128 + t];
        xb[g*128 + t] = lrelu01(a);
    }
}

// ---------- final MLP: concat -> 256 -> 64 -> 1 -> sigmoid ----------
__global__ __launch_bounds__(256) void k_final(const float* __restrict__ xb1, const float* __restrict__ xb2,
                      const float* __restrict__ fc1W, const float* __restrict__ fc1b,
                      const float* __restrict__ fc2W, const float* __restrict__ fc2b,
                      const float* __restrict__ outW, const float* __restrict__ outb,
                      float* __restrict__ out){
    __shared__ float xc[256], y1[256], y2[64];
    int g = blockIdx.x, t = threadIdx.x;
    xc[t] = (t < 128) ? xb1[g*128 + t] : xb2[g*128 + (t-128)];
    __syncthreads();
    float a = fc1b[t];
    for (int k=0;k<256;k++) a += xc[k]*fc1W[k*256 + t];
    y1[t] = lrelu01(a);
    __syncthreads();
    if (t < 64){
        float a2 = fc2b[t];
        for (int k=0;k<256;k++) a2 += y1[k]*fc2W[k*64 + t];
        y2[t] = lrelu01(a2);
    }
    __syncthreads();
    if (t == 0){
        float z = outb[0];
        for (int k=0;k<64;k++) z += y2[k]*outW[k];
        out[g] = 1.f/(1.f + expf(-z));
    }
}

extern "C" void kernel_launch(void* const* d_in, const int* in_sizes, int n_in,
                              void* d_out, int out_size, void* d_ws, size_t ws_size,
                              hipStream_t stream){
    const float* xs[2]      = {(const float*)d_in[0],  (const float*)d_in[5]};
    const int*   eis[2][3]  = {{(const int*)d_in[1],(const int*)d_in[2],(const int*)d_in[3]},
                               {(const int*)d_in[6],(const int*)d_in[7],(const int*)d_in[8]}};
    const int*   batches[2] = {(const int*)d_in[4],  (const int*)d_in[9]};
    const float* Wd[2]      = {(const float*)d_in[10],(const float*)d_in[16]};
    const float* avs[2][2]  = {{(const float*)d_in[11],(const float*)d_in[12]},
                               {(const float*)d_in[17],(const float*)d_in[18]}};
    const float* bvs[2]     = {(const float*)d_in[13],(const float*)d_in[19]};
    const float* pWs[2]     = {(const float*)d_in[14],(const float*)d_in[20]};
    const float* pbs[2]     = {(const float*)d_in[15],(const float*)d_in[21]};
    const float* fc1W=(const float*)d_in[22], *fc1b=(const float*)d_in[23];
    const float* fc2W=(const float*)d_in[24], *fc2b=(const float*)d_in[25];
    const float* outW=(const float*)d_in[26], *outb=(const float*)d_in[27];
    float* out = (float*)d_out;

    char* ws = (char*)d_ws;
    size_t o = 0;
    auto alloc = [&](size_t bytes)->char*{ char* p = ws + o; o += (bytes + 511) & ~(size_t)511; return p; };
    float*  h    = (float*)alloc((size_t)N_NODES*D_HID*4);
    float*  hacc = (float*)alloc((size_t)N_NODES*D_HID*4);
    float*  als  = (float*)alloc((size_t)N_NODES*4);
    float*  ald  = (float*)alloc((size_t)N_NODES*4);
    int*    deg  = (int*)  alloc((size_t)(N_NODES+1)*4);
    int*    offs = (int*)  alloc((size_t)(N_NODES+1)*4);
    int*    cur  = (int*)  alloc((size_t)N_NODES*4);
    int*    esrc = (int*)  alloc((size_t)N_EDGES*4);
    ushort* Wt   = (ushort*)alloc((size_t)D_HID*F_IN*2);
    float*  xb1  = (float*)alloc((size_t)N_GRAPH*D_HID*4);
    float*  xb2  = (float*)alloc((size_t)N_GRAPH*D_HID*4);

    for (int br=0; br<2; br++){
        float* xb = br ? xb2 : xb1;
        k_cast_wt<<<(D_HID*F_IN)/256, 256, 0, stream>>>(Wd[br], Wt);
        k_gemm<<<(N_NODES+BM-1)/BM, 256, 0, stream>>>(xs[br], Wt, h, N_NODES);
        k_al<<<(N_NODES+3)/4, 256, 0, stream>>>(h, avs[br][0], avs[br][1], als, ald);
        for (int hop=0; hop<3; hop++){
            const int* ei = eis[br][hop];           // ei[0:E]=src, ei[E:2E]=dst
            k_zero <<<(N_NODES+1+255)/256, 256, 0, stream>>>(deg, N_NODES+1);
            k_count<<<(N_EDGES+255)/256, 256, 0, stream>>>(ei + N_EDGES, deg);
            k_scan <<<1, 1024, 0, stream>>>(deg, offs, cur);
            k_fill <<<(N_EDGES+255)/256, 256, 0, stream>>>(ei, ei + N_EDGES, cur, esrc);
            k_gat  <<<(N_NODES+3)/4, 256, 0, stream>>>(offs, esrc, als, ald, h, bvs[br], hacc, hop==0);
        }
        k_pool_fc<<<N_GRAPH, 256, 0, stream>>>(hacc, batches[br], pWs[br], pbs[br], xb);
    }
    k_final<<<N_GRAPH, 256, 0, stream>>>(xb1, xb2, fc1W, fc1b, fc2W, fc2b, outW, outb, out);
}

// Round 2
// 1038.216 us; speedup vs baseline: 1.7157x; 1.7157x over previous
//
#include <hip/hip_runtime.h>
#include <hip/hip_bf16.h>
#include <math.h>

#define N_NODES 50000
#define N_EDGES 800000
#define N_GRAPH 128
#define F_IN    1024
#define D_HID   128
#define NT3     (3*N_NODES)
#define SCB     1024
#define NBLK    ((NT3+SCB-1)/SCB)

typedef __bf16 bf16x8 __attribute__((ext_vector_type(8)));
typedef float  f32x4  __attribute__((ext_vector_type(4)));

__device__ __forceinline__ float lrelu01(float x){ return x > 0.f ? x : 0.01f*x; }
__device__ __forceinline__ float lrelu02(float x){ return x > 0.f ? x : 0.2f*x; }
__device__ __forceinline__ ushort f2bf(float v){
    __hip_bfloat16 hb = __float2bfloat16(v);
    return *reinterpret_cast<ushort*>(&hb);
}
__device__ __forceinline__ float2 bfu2(uint u){
    union { uint i; float f; } a, b;
    a.i = u << 16; b.i = u & 0xFFFF0000u;
    return make_float2(a.f, b.f);
}

// ---------- W [1024][128] f32 -> Wt [128][1024] bf16 ----------
__global__ void k_cast_wt(const float* __restrict__ W, ushort* __restrict__ Wt){
    int t = blockIdx.x*256 + threadIdx.x;
    int n = t >> 10, k = t & 1023;
    Wt[t] = f2bf(W[k*D_HID + n]);
}

// ---------- GEMM: Hb[M][128](bf16) = x[M][1024] @ W ----------
#define BM  64
#define BK  64
#define LDP 72

__global__ __launch_bounds__(256) void k_gemm(const float* __restrict__ X,
                                              const ushort* __restrict__ Wt,
                                              ushort* __restrict__ Hb, int M){
    __shared__ ushort As[BM*LDP];
    __shared__ ushort Bs[D_HID*LDP];
    int tid  = threadIdx.x;
    int m0   = blockIdx.x * BM;
    int lane = tid & 63;
    int wave = tid >> 6;
    int l15 = lane & 15, l4 = lane >> 4;
    int wcol = wave * 32;

    float4 pa[4];
    uint4  pb[4];

    auto loadA = [&](int kt){
        #pragma unroll
        for (int i=0;i<4;i++){
            int q = tid + i*256; int row = q >> 4; int kq = (q & 15) << 2;
            int gr = m0 + row;
            pa[i] = (gr < M) ? *reinterpret_cast<const float4*>(X + (size_t)gr*F_IN + kt + kq)
                             : make_float4(0.f,0.f,0.f,0.f);
        }
    };
    auto loadB = [&](int kt){
        #pragma unroll
        for (int i=0;i<4;i++){
            int q = tid + i*256; int row = q >> 3; int ck = q & 7;
            pb[i] = *reinterpret_cast<const uint4*>(Wt + row*F_IN + kt + ck*8);
        }
    };
    auto stage = [&](){
        #pragma unroll
        for (int i=0;i<4;i++){
            int q = tid + i*256; int row = q >> 4; int kq = (q & 15) << 2;
            ushort4 b; b.x=f2bf(pa[i].x); b.y=f2bf(pa[i].y); b.z=f2bf(pa[i].z); b.w=f2bf(pa[i].w);
            *reinterpret_cast<ushort4*>(&As[row*LDP + kq]) = b;
        }
        #pragma unroll
        for (int i=0;i<4;i++){
            int q = tid + i*256; int row = q >> 3; int ck = q & 7;
            *reinterpret_cast<uint2*>(&Bs[row*LDP + ck*8])     = make_uint2(pb[i].x, pb[i].y);
            *reinterpret_cast<uint2*>(&Bs[row*LDP + ck*8 + 4]) = make_uint2(pb[i].z, pb[i].w);
        }
    };

    f32x4 acc[4][2];
    #pragma unroll
    for (int i=0;i<4;i++) for (int j=0;j<2;j++) acc[i][j] = (f32x4){0.f,0.f,0.f,0.f};

    loadA(0); loadB(0);
    for (int kt = 0; kt < F_IN; kt += BK) {
        stage();
        __syncthreads();
        if (kt + BK < F_IN){ loadA(kt+BK); loadB(kt+BK); }
        #pragma unroll
        for (int kk = 0; kk < BK; kk += 32) {
            bf16x8 af[4], bfr[2];
            #pragma unroll
            for (int mi=0;mi<4;mi++)
                af[mi] = *reinterpret_cast<const bf16x8*>(&As[(mi*16+l15)*LDP + kk + l4*8]);
            #pragma unroll
            for (int ni=0;ni<2;ni++)
                bfr[ni] = *reinterpret_cast<const bf16x8*>(&Bs[(wcol+ni*16+l15)*LDP + kk + l4*8]);
            #pragma unroll
            for (int mi=0;mi<4;mi++)
                #pragma unroll
                for (int ni=0;ni<2;ni++)
                    acc[mi][ni] = __builtin_amdgcn_mfma_f32_16x16x32_bf16(af[mi], bfr[ni], acc[mi][ni], 0,0,0);
        }
        __syncthreads();
    }
    #pragma unroll
    for (int mi=0;mi<4;mi++){
        #pragma unroll
        for (int jj=0;jj<4;jj++){
            int r = m0 + mi*16 + l4*4 + jj;
            if (r < M){
                #pragma unroll
                for (int ni=0;ni<2;ni++){
                    int c = wcol + ni*16 + l15;
                    Hb[(size_t)r*D_HID + c] = f2bf(acc[mi][ni][jj]);
                }
            }
        }
    }
}

// ---------- al_s/al_d from bf16 h ----------
__global__ __launch_bounds__(256) void k_al(const uint* __restrict__ Hb2,
                    const float* __restrict__ asrc, const float* __restrict__ adst,
                    float* __restrict__ als, float* __restrict__ ald){
    int lane = threadIdx.x & 63;
    int row  = blockIdx.x*4 + (threadIdx.x >> 6);
    if (row >= N_NODES) return;
    float2 v  = bfu2(Hb2[(size_t)row*64 + lane]);
    float2 as = *reinterpret_cast<const float2*>(asrc + 2*lane);
    float2 ad = *reinterpret_cast<const float2*>(adst + 2*lane);
    float ds = v.x*as.x + v.y*as.y;
    float dd = v.x*ad.x + v.y*ad.y;
    for (int o=32;o;o>>=1){ ds += __shfl_xor(ds,o); dd += __shfl_xor(dd,o); }
    if (lane==0){ als[row]=ds; ald[row]=dd; }
}

// ---------- CSR build (all 3 hops at once) ----------
__global__ void k_zero(int* __restrict__ p, int n){
    int i = blockIdx.x*256 + threadIdx.x;
    if (i < n) p[i] = 0;
}
__global__ void k_count3(const int* __restrict__ e1, const int* __restrict__ e2,
                         const int* __restrict__ e3, int* __restrict__ deg){
    int idx = blockIdx.x*256 + threadIdx.x;
    if (idx >= 3*N_EDGES) return;
    int hop = idx / N_EDGES, e = idx - hop*N_EDGES;
    const int* ei = (hop==0) ? e1 : (hop==1) ? e2 : e3;
    atomicAdd(&deg[hop*N_NODES + ei[N_EDGES + e]], 1);
}
__global__ __launch_bounds__(256) void k_part(const int* __restrict__ deg, int* __restrict__ bsum){
    __shared__ int sd[256];
    int b = blockIdx.x, t = threadIdx.x;
    int base = b*SCB + t*4;
    int s = 0;
    if (base + 3 < NT3){
        int4 v = *reinterpret_cast<const int4*>(deg + base);
        s = v.x + v.y + v.z + v.w;
    } else {
        for (int i=0;i<4;i++){ int idx = base+i; if (idx < NT3) s += deg[idx]; }
    }
    sd[t] = s; __syncthreads();
    for (int o=128;o;o>>=1){ if (t<o) sd[t]+=sd[t+o]; __syncthreads(); }
    if (t==0) bsum[b] = sd[0];
}
__global__ __launch_bounds__(256) void k_bsum(const int* __restrict__ bsum, int* __restrict__ bbase){
    __shared__ int s[256];
    int t = threadIdx.x;
    int v = (t < NBLK) ? bsum[t] : 0;
    s[t] = v; __syncthreads();
    for (int o=1;o<256;o<<=1){
        int u = (t>=o) ? s[t-o] : 0;
        __syncthreads(); s[t] += u; __syncthreads();
    }
    if (t < NBLK) bbase[t] = s[t] - v;
}
__global__ __launch_bounds__(256) void k_off(const int* __restrict__ deg, const int* __restrict__ bbase,
                                             int* __restrict__ offs, int* __restrict__ cur){
    __shared__ int sd[256];
    int b = blockIdx.x, t = threadIdx.x;
    int base = b*SCB + t*4;
    int v[4]; int s = 0;
    #pragma unroll
    for (int i=0;i<4;i++){ int idx = base+i; v[i] = (idx < NT3) ? deg[idx] : 0; s += v[i]; }
    sd[t] = s; __syncthreads();
    for (int o=1;o<256;o<<=1){
        int u = (t>=o) ? sd[t-o] : 0;
        __syncthreads(); sd[t] += u; __syncthreads();
    }
    int run = bbase[b] + sd[t] - s;
    #pragma unroll
    for (int i=0;i<4;i++){ int idx = base+i; if (idx < NT3){ offs[idx]=run; cur[idx]=run; run += v[i]; } }
    if (b == (int)gridDim.x-1 && t == 255) offs[NT3] = run;
}
__global__ void k_fill3(const int* __restrict__ e1, const int* __restrict__ e2,
                        const int* __restrict__ e3, int* __restrict__ cur, int* __restrict__ esrc){
    int idx = blockIdx.x*256 + threadIdx.x;
    if (idx >= 3*N_EDGES) return;
    int hop = idx / N_EDGES, e = idx - hop*N_EDGES;
    const int* ei = (hop==0) ? e1 : (hop==1) ? e2 : e3;
    int p = atomicAdd(&cur[hop*N_NODES + ei[N_EDGES + e]], 1);
    esrc[p] = ei[e];
}

// ---------- GAT aggregate, all 3 hops per dst wave ----------
__global__ __launch_bounds__(256) void k_gat3(const int* __restrict__ offs, const int* __restrict__ esrc,
                     const float* __restrict__ als, const float* __restrict__ ald,
                     const uint* __restrict__ Hb2, const float* __restrict__ bvec,
                     float* __restrict__ hacc){
    int lane = threadIdx.x & 63;
    int d = blockIdx.x*4 + (threadIdx.x >> 6);
    if (d >= N_NODES) return;
    float aldd  = ald[d];
    float eself = lrelu02(als[d] + aldd);
    float exs   = expf(fminf(eself, 50.f));
    float2 hself = bfu2(Hb2[(size_t)d*64 + lane]);
    float2 bv = *reinterpret_cast<const float2*>(bvec + 2*lane);
    float2 tot = make_float2(0.f, 0.f);
    for (int hop=0; hop<3; hop++){
        int s0 = offs[hop*N_NODES + d];
        int s1 = offs[hop*N_NODES + d + 1];
        int deg = s1 - s0;
        float2 acc = make_float2(exs*hself.x, exs*hself.y);
        float es = 0.f;
        for (int base=0; base<deg; base+=64){
            int j = base + lane;
            int s = 0; float ex = 0.f;
            if (j < deg){
                s = esrc[s0 + j];
                ex = expf(fminf(lrelu02(als[s] + aldd), 50.f));
            }
            es += ex;
            int cnt = min(64, deg - base);
            int jj = 0;
            for (; jj+4 <= cnt; jj += 4){
                int   sa = __shfl(s, jj),   sb = __shfl(s, jj+1);
                int   sc = __shfl(s, jj+2), sd2= __shfl(s, jj+3);
                float ea = __shfl(ex, jj),  eb = __shfl(ex, jj+1);
                float ec = __shfl(ex, jj+2),ed = __shfl(ex, jj+3);
                uint ua = Hb2[(size_t)sa*64 + lane];
                uint ub = Hb2[(size_t)sb*64 + lane];
                uint uc = Hb2[(size_t)sc*64 + lane];
                uint ud = Hb2[(size_t)sd2*64 + lane];
                float2 va = bfu2(ua), vb = bfu2(ub), vc = bfu2(uc), vd = bfu2(ud);
                acc.x += ea*va.x + eb*vb.x + ec*vc.x + ed*vd.x;
                acc.y += ea*va.y + eb*vb.y + ec*vc.y + ed*vd.y;
            }
            for (; jj<cnt; jj++){
                int sj = __shfl(s, jj); float ej = __shfl(ex, jj);
                float2 v = bfu2(Hb2[(size_t)sj*64 + lane]);
                acc.x += ej*v.x; acc.y += ej*v.y;
            }
        }
        for (int o=32;o;o>>=1) es += __shfl_xor(es,o);
        float inv = 1.f / (es + exs);
        tot.x += lrelu01(acc.x*inv + bv.x);
        tot.y += lrelu01(acc.y*inv + bv.y);
    }
    *reinterpret_cast<float2*>(hacc + (size_t)d*D_HID + 2*lane) = tot;
}

// ---------- mean-pool per graph + branch FC ----------
__global__ __launch_bounds__(256) void k_pool_fc(const float* __restrict__ hacc,
                    const int* __restrict__ batch,
                    const float* __restrict__ fcW, const float* __restrict__ fcb,
                    float* __restrict__ xb){
    __shared__ float sums[2][128];
    __shared__ float pl[128];
    int g = blockIdx.x;
    int t = threadIdx.x;
    int lo=0, hi=N_NODES;
    while (lo<hi){ int mid=(lo+hi)>>1; if (batch[mid] < g) lo=mid+1; else hi=mid; }
    int s = lo;
    lo = s; hi = N_NODES;
    while (lo<hi){ int mid=(lo+hi)>>1; if (batch[mid] < g+1) lo=mid+1; else hi=mid; }
    int e = lo;
    int f = t & 127, half = t >> 7;
    float sum = 0.f;
    for (int n=s+half; n<e; n+=2) sum += hacc[(size_t)n*D_HID + f];
    sums[half][f] = sum;
    __syncthreads();
    if (t < 128){
        float cnt = (float)(e - s);
        pl[t] = (sums[0][t] + sums[1][t]) / fmaxf(cnt, 1.0f);
    }
    __syncthreads();
    if (t < 128){
        float a = fcb[t];
        for (int k=0;k<128;k++) a += pl[k]*fcW[k*128 + t];
        xb[g*128 + t] = lrelu01(a);
    }
}

// ---------- final MLP ----------
__global__ __launch_bounds__(256) void k_final(const float* __restrict__ xb1, const float* __restrict__ xb2,
                      const float* __restrict__ fc1W, const float* __restrict__ fc1b,
                      const float* __restrict__ fc2W, const float* __restrict__ fc2b,
                      const float* __restrict__ outW, const float* __restrict__ outb,
                      float* __restrict__ out){
    __shared__ float xc[256], y1[256], y2[64];
    int g = blockIdx.x, t = threadIdx.x;
    xc[t] = (t < 128) ? xb1[g*128 + t] : xb2[g*128 + (t-128)];
    __syncthreads();
    float a = fc1b[t];
    for (int k=0;k<256;k++) a += xc[k]*fc1W[k*256 + t];
    y1[t] = lrelu01(a);
    __syncthreads();
    if (t < 64){
        float a2 = fc2b[t];
        for (int k=0;k<256;k++) a2 += y1[k]*fc2W[k*64 + t];
        y2[t] = lrelu01(a2);
    }
    __syncthreads();
    if (t == 0){
        float z = outb[0];
        for (int k=0;k<64;k++) z += y2[k]*outW[k];
        out[g] = 1.f/(1.f + expf(-z));
    }
}

extern "C" void kernel_launch(void* const* d_in, const int* in_sizes, int n_in,
                              void* d_out, int out_size, void* d_ws, size_t ws_size,
                              hipStream_t stream){
    const float* xs[2]      = {(const float*)d_in[0],  (const float*)d_in[5]};
    const int*   eis[2][3]  = {{(const int*)d_in[1],(const int*)d_in[2],(const int*)d_in[3]},
                               {(const int*)d_in[6],(const int*)d_in[7],(const int*)d_in[8]}};
    const int*   batches[2] = {(const int*)d_in[4],  (const int*)d_in[9]};
    const float* Wd[2]      = {(const float*)d_in[10],(const float*)d_in[16]};
    const float* avs[2][2]  = {{(const float*)d_in[11],(const float*)d_in[12]},
                               {(const float*)d_in[17],(const float*)d_in[18]}};
    const float* bvs[2]     = {(const float*)d_in[13],(const float*)d_in[19]};
    const float* pWs[2]     = {(const float*)d_in[14],(const float*)d_in[20]};
    const float* pbs[2]     = {(const float*)d_in[15],(const float*)d_in[21]};
    const float* fc1W=(const float*)d_in[22], *fc1b=(const float*)d_in[23];
    const float* fc2W=(const float*)d_in[24], *fc2b=(const float*)d_in[25];
    const float* outW=(const float*)d_in[26], *outb=(const float*)d_in[27];
    float* out = (float*)d_out;

    char* ws = (char*)d_ws;
    size_t o = 0;
    auto alloc = [&](size_t bytes)->char*{ char* p = ws + o; o += (bytes + 511) & ~(size_t)511; return p; };
    ushort* Hb   = (ushort*)alloc((size_t)N_NODES*D_HID*2);
    float*  hacc = (float*) alloc((size_t)N_NODES*D_HID*4);
    float*  als  = (float*) alloc((size_t)N_NODES*4);
    float*  ald  = (float*) alloc((size_t)N_NODES*4);
    int*    deg3 = (int*)   alloc((size_t)(NT3+1)*4);
    int*    offs3= (int*)   alloc((size_t)(NT3+1)*4);
    int*    cur3 = (int*)   alloc((size_t)NT3*4);
    int*    esrc3= (int*)   alloc((size_t)3*N_EDGES*4);
    int*    bsum = (int*)   alloc((size_t)256*4);
    int*    bbase= (int*)   alloc((size_t)256*4);
    ushort* Wt   = (ushort*)alloc((size_t)D_HID*F_IN*2);
    float*  xb1  = (float*) alloc((size_t)N_GRAPH*D_HID*4);
    float*  xb2  = (float*) alloc((size_t)N_GRAPH*D_HID*4);

    for (int br=0; br<2; br++){
        float* xb = br ? xb2 : xb1;
        k_cast_wt<<<(D_HID*F_IN)/256, 256, 0, stream>>>(Wd[br], Wt);
        k_gemm<<<(N_NODES+BM-1)/BM, 256, 0, stream>>>(xs[br], Wt, Hb, N_NODES);
        k_al<<<(N_NODES+3)/4, 256, 0, stream>>>((const uint*)Hb, avs[br][0], avs[br][1], als, ald);
        k_zero  <<<(NT3+255)/256, 256, 0, stream>>>(deg3, NT3);
        k_count3<<<(3*N_EDGES+255)/256, 256, 0, stream>>>(eis[br][0], eis[br][1], eis[br][2], deg3);
        k_part  <<<NBLK, 256, 0, stream>>>(deg3, bsum);
        k_bsum  <<<1, 256, 0, stream>>>(bsum, bbase);
        k_off   <<<NBLK, 256, 0, stream>>>(deg3, bbase, offs3, cur3);
        k_fill3 <<<(3*N_EDGES+255)/256, 256, 0, stream>>>(eis[br][0], eis[br][1], eis[br][2], cur3, esrc3);
        k_gat3  <<<(N_NODES+3)/4, 256, 0, stream>>>(offs3, esrc3, als, ald, (const uint*)Hb, bvs[br], hacc);
        k_pool_fc<<<N_GRAPH, 256, 0, stream>>>(hacc, batches[br], pWs[br], pbs[br], xb);
    }
    k_final<<<N_GRAPH, 256, 0, stream>>>(xb1, xb2, fc1W, fc1b, fc2W, fc2b, outW, outb, out);
}

// Round 3
// 569.336 us; speedup vs baseline: 3.1287x; 1.8236x over previous
//
#include <hip/hip_runtime.h>
#include <hip/hip_bf16.h>
#include <math.h>

#define N_NODES 50000
#define N_EDGES 800000
#define N_GRAPH 128
#define F_IN    1024
#define D_HID   128
#define NT3     (3*N_NODES)

// bucketed CSR build
#define NPB_SH  9
#define NPB     512
#define NB      ((NT3 + NPB - 1) / NPB)   // 293
#define CAP     10240
#define EPB     4096

typedef __bf16 bf16x8 __attribute__((ext_vector_type(8)));
typedef float  f32x4  __attribute__((ext_vector_type(4)));

__device__ __forceinline__ float lrelu01(float x){ return x > 0.f ? x : 0.01f*x; }
__device__ __forceinline__ float lrelu02(float x){ return x > 0.f ? x : 0.2f*x; }
__device__ __forceinline__ ushort f2bf(float v){
    __hip_bfloat16 hb = __float2bfloat16(v);
    return *reinterpret_cast<ushort*>(&hb);
}
__device__ __forceinline__ float2 bfu2(uint u){
    union { uint i; float f; } a, b;
    a.i = u << 16; b.i = u & 0xFFFF0000u;
    return make_float2(a.f, b.f);
}

// ---------- W [1024][128] f32 -> Wt [128][1024] bf16 ----------
__global__ void k_cast_wt(const float* __restrict__ W, ushort* __restrict__ Wt){
    int t = blockIdx.x*256 + threadIdx.x;
    int n = t >> 10, k = t & 1023;
    Wt[t] = f2bf(W[k*D_HID + n]);
}

// ---------- GEMM: Hb[M][128](bf16) = x[M][1024] @ W ----------
#define BM  64
#define BK  64
#define LDP 72

__global__ __launch_bounds__(256) void k_gemm(const float* __restrict__ X,
                                              const ushort* __restrict__ Wt,
                                              ushort* __restrict__ Hb, int M){
    __shared__ ushort As[BM*LDP];
    __shared__ ushort Bs[D_HID*LDP];
    int tid  = threadIdx.x;
    int m0   = blockIdx.x * BM;
    int lane = tid & 63;
    int wave = tid >> 6;
    int l15 = lane & 15, l4 = lane >> 4;
    int wcol = wave * 32;

    float4 pa[4];
    uint4  pb[4];

    auto loadA = [&](int kt){
        #pragma unroll
        for (int i=0;i<4;i++){
            int q = tid + i*256; int row = q >> 4; int kq = (q & 15) << 2;
            int gr = m0 + row;
            pa[i] = (gr < M) ? *reinterpret_cast<const float4*>(X + (size_t)gr*F_IN + kt + kq)
                             : make_float4(0.f,0.f,0.f,0.f);
        }
    };
    auto loadB = [&](int kt){
        #pragma unroll
        for (int i=0;i<4;i++){
            int q = tid + i*256; int row = q >> 3; int ck = q & 7;
            pb[i] = *reinterpret_cast<const uint4*>(Wt + row*F_IN + kt + ck*8);
        }
    };
    auto stage = [&](){
        #pragma unroll
        for (int i=0;i<4;i++){
            int q = tid + i*256; int row = q >> 4; int kq = (q & 15) << 2;
            ushort4 b; b.x=f2bf(pa[i].x); b.y=f2bf(pa[i].y); b.z=f2bf(pa[i].z); b.w=f2bf(pa[i].w);
            *reinterpret_cast<ushort4*>(&As[row*LDP + kq]) = b;
        }
        #pragma unroll
        for (int i=0;i<4;i++){
            int q = tid + i*256; int row = q >> 3; int ck = q & 7;
            *reinterpret_cast<uint2*>(&Bs[row*LDP + ck*8])     = make_uint2(pb[i].x, pb[i].y);
            *reinterpret_cast<uint2*>(&Bs[row*LDP + ck*8 + 4]) = make_uint2(pb[i].z, pb[i].w);
        }
    };

    f32x4 acc[4][2];
    #pragma unroll
    for (int i=0;i<4;i++) for (int j=0;j<2;j++) acc[i][j] = (f32x4){0.f,0.f,0.f,0.f};

    loadA(0); loadB(0);
    for (int kt = 0; kt < F_IN; kt += BK) {
        stage();
        __syncthreads();
        if (kt + BK < F_IN){ loadA(kt+BK); loadB(kt+BK); }
        #pragma unroll
        for (int kk = 0; kk < BK; kk += 32) {
            bf16x8 af[4], bfr[2];
            #pragma unroll
            for (int mi=0;mi<4;mi++)
                af[mi] = *reinterpret_cast<const bf16x8*>(&As[(mi*16+l15)*LDP + kk + l4*8]);
            #pragma unroll
            for (int ni=0;ni<2;ni++)
                bfr[ni] = *reinterpret_cast<const bf16x8*>(&Bs[(wcol+ni*16+l15)*LDP + kk + l4*8]);
            #pragma unroll
            for (int mi=0;mi<4;mi++)
                #pragma unroll
                for (int ni=0;ni<2;ni++)
                    acc[mi][ni] = __builtin_amdgcn_mfma_f32_16x16x32_bf16(af[mi], bfr[ni], acc[mi][ni], 0,0,0);
        }
        __syncthreads();
    }
    #pragma unroll
    for (int mi=0;mi<4;mi++){
        #pragma unroll
        for (int jj=0;jj<4;jj++){
            int r = m0 + mi*16 + l4*4 + jj;
            if (r < M){
                #pragma unroll
                for (int ni=0;ni<2;ni++){
                    int c = wcol + ni*16 + l15;
                    Hb[(size_t)r*D_HID + c] = f2bf(acc[mi][ni][jj]);
                }
            }
        }
    }
}

// ---------- al_s/al_d from bf16 h ----------
__global__ __launch_bounds__(256) void k_al(const uint* __restrict__ Hb2,
                    const float* __restrict__ asrc, const float* __restrict__ adst,
                    float* __restrict__ als, float* __restrict__ ald){
    int lane = threadIdx.x & 63;
    int row  = blockIdx.x*4 + (threadIdx.x >> 6);
    if (row >= N_NODES) return;
    float2 v  = bfu2(Hb2[(size_t)row*64 + lane]);
    float2 as = *reinterpret_cast<const float2*>(asrc + 2*lane);
    float2 ad = *reinterpret_cast<const float2*>(adst + 2*lane);
    float ds = v.x*as.x + v.y*as.y;
    float dd = v.x*ad.x + v.y*ad.y;
    for (int o=32;o;o>>=1){ ds += __shfl_xor(ds,o); dd += __shfl_xor(dd,o); }
    if (lane==0){ als[row]=ds; ald[row]=dd; }
}

// ---------- bucketed CSR ----------
__global__ void k_zero(int* __restrict__ p, int n){
    int i = blockIdx.x*256 + threadIdx.x;
    if (i < n) p[i] = 0;
}

__global__ __launch_bounds__(256) void k_bin(const int* __restrict__ e1, const int* __restrict__ e2,
                                             const int* __restrict__ e3,
                                             int* __restrict__ gcur, uint2* __restrict__ pairs){
    __shared__ int hist[NB];
    __shared__ int start[NB];
    int tid = threadIdx.x;
    for (int b=tid; b<NB; b+=256) hist[b]=0;
    __syncthreads();
    long base = (long)blockIdx.x * EPB;
    int myb[16], mysrc[16], myvd[16];
    #pragma unroll
    for (int i=0;i<16;i++){
        long idx = base + i*256 + tid;
        int b = -1, src = 0, vd = 0;
        if (idx < 3L*N_EDGES){
            int hop = (idx >= 2L*N_EDGES) ? 2 : (idx >= (long)N_EDGES) ? 1 : 0;
            int e   = (int)(idx - (long)hop*N_EDGES);
            const int* ei = (hop==0) ? e1 : (hop==1) ? e2 : e3;
            src = ei[e];
            vd  = hop*N_NODES + ei[N_EDGES + e];
            b   = vd >> NPB_SH;
            atomicAdd(&hist[b], 1);
        }
        myb[i]=b; mysrc[i]=src; myvd[i]=vd;
    }
    __syncthreads();
    for (int b=tid; b<NB; b+=256){
        int h = hist[b];
        start[b] = (h>0) ? atomicAdd(&gcur[b], h) : 0;
    }
    __syncthreads();
    for (int b=tid; b<NB; b+=256) hist[b] = start[b];
    __syncthreads();
    #pragma unroll
    for (int i=0;i<16;i++){
        int b = myb[i];
        if (b >= 0){
            int pos = atomicAdd(&hist[b], 1);
            if (pos < CAP) pairs[(size_t)b*CAP + pos] = make_uint2((uint)mysrc[i], (uint)myvd[i]);
        }
    }
}

__global__ __launch_bounds__(512) void k_bktscan(const int* __restrict__ gcur,
                                                 int* __restrict__ bktbase, int* __restrict__ offs3){
    __shared__ int s[512];
    int t = threadIdx.x;
    int v = (t < NB) ? min(gcur[t], CAP) : 0;
    s[t] = v; __syncthreads();
    for (int o=1;o<512;o<<=1){
        int u = (t>=o) ? s[t-o] : 0;
        __syncthreads(); s[t] += u; __syncthreads();
    }
    if (t < NB) bktbase[t] = s[t] - v;
    if (t == NB-1) offs3[NT3] = s[t];
}

__global__ __launch_bounds__(256) void k_localcsr(const int* __restrict__ gcur,
                                                  const int* __restrict__ bktbase,
                                                  const uint2* __restrict__ pairs,
                                                  int* __restrict__ offs3, int* __restrict__ esrc){
    __shared__ int deg[NPB];
    __shared__ int cur[NPB];
    __shared__ int ss[256];
    int b = blockIdx.x, t = threadIdx.x;
    int cnt = min(gcur[b], CAP);
    deg[t]=0; deg[t+256]=0;
    __syncthreads();
    const uint2* pb = pairs + (size_t)b*CAP;
    for (int i=t; i<cnt; i+=256) atomicAdd(&deg[pb[i].y & (NPB-1)], 1);
    __syncthreads();
    int a0 = deg[2*t], a1 = deg[2*t+1];
    int ps = a0 + a1;
    ss[t] = ps; __syncthreads();
    for (int o=1;o<256;o<<=1){
        int u = (t>=o) ? ss[t-o] : 0;
        __syncthreads(); ss[t] += u; __syncthreads();
    }
    int ex = ss[t] - ps;
    __syncthreads();
    deg[2*t] = ex; deg[2*t+1] = ex + a0;
    cur[2*t] = ex; cur[2*t+1] = ex + a0;
    __syncthreads();
    int base = bktbase[b];
    int vd0 = b << NPB_SH;
    for (int l=t; l<NPB; l+=256){
        int vd = vd0 + l;
        if (vd < NT3) offs3[vd] = base + deg[l];
    }
    for (int i=t; i<cnt; i+=256){
        uint2 p = pb[i];
        int pos = atomicAdd(&cur[p.y & (NPB-1)], 1);
        esrc[base + pos] = (int)p.x;
    }
}

// ---------- GAT aggregate, all 3 hops per dst wave ----------
__global__ __launch_bounds__(256) void k_gat3(const int* __restrict__ offs, const int* __restrict__ esrc,
                     const float* __restrict__ als, const float* __restrict__ ald,
                     const uint* __restrict__ Hb2, const float* __restrict__ bvec,
                     float* __restrict__ hacc){
    int lane = threadIdx.x & 63;
    int d = blockIdx.x*4 + (threadIdx.x >> 6);
    if (d >= N_NODES) return;
    float aldd  = ald[d];
    float eself = lrelu02(als[d] + aldd);
    float exs   = expf(fminf(eself, 50.f));
    float2 hself = bfu2(Hb2[(size_t)d*64 + lane]);
    float2 bv = *reinterpret_cast<const float2*>(bvec + 2*lane);
    float2 tot = make_float2(0.f, 0.f);
    for (int hop=0; hop<3; hop++){
        int s0 = offs[hop*N_NODES + d];
        int s1 = offs[hop*N_NODES + d + 1];
        int deg = s1 - s0;
        float2 acc = make_float2(exs*hself.x, exs*hself.y);
        float es = 0.f;
        for (int base=0; base<deg; base+=64){
            int j = base + lane;
            int s = 0; float ex = 0.f;
            if (j < deg){
                s = esrc[s0 + j];
                ex = expf(fminf(lrelu02(als[s] + aldd), 50.f));
            }
            es += ex;
            int cnt = min(64, deg - base);
            int jj = 0;
            for (; jj+4 <= cnt; jj += 4){
                int   sa = __shfl(s, jj),   sb = __shfl(s, jj+1);
                int   sc = __shfl(s, jj+2), sd2= __shfl(s, jj+3);
                float ea = __shfl(ex, jj),  eb = __shfl(ex, jj+1);
                float ec = __shfl(ex, jj+2),ed = __shfl(ex, jj+3);
                uint ua = Hb2[(size_t)sa*64 + lane];
                uint ub = Hb2[(size_t)sb*64 + lane];
                uint uc = Hb2[(size_t)sc*64 + lane];
                uint ud = Hb2[(size_t)sd2*64 + lane];
                float2 va = bfu2(ua), vb = bfu2(ub), vc = bfu2(uc), vd = bfu2(ud);
                acc.x += ea*va.x + eb*vb.x + ec*vc.x + ed*vd.x;
                acc.y += ea*va.y + eb*vb.y + ec*vc.y + ed*vd.y;
            }
            for (; jj<cnt; jj++){
                int sj = __shfl(s, jj); float ej = __shfl(ex, jj);
                float2 v = bfu2(Hb2[(size_t)sj*64 + lane]);
                acc.x += ej*v.x; acc.y += ej*v.y;
            }
        }
        for (int o=32;o;o>>=1) es += __shfl_xor(es,o);
        float inv = 1.f / (es + exs);
        tot.x += lrelu01(acc.x*inv + bv.x);
        tot.y += lrelu01(acc.y*inv + bv.y);
    }
    *reinterpret_cast<float2*>(hacc + (size_t)d*D_HID + 2*lane) = tot;
}

// ---------- mean-pool per graph + branch FC ----------
__global__ __launch_bounds__(256) void k_pool_fc(const float* __restrict__ hacc,
                    const int* __restrict__ batch,
                    const float* __restrict__ fcW, const float* __restrict__ fcb,
                    float* __restrict__ xb){
    __shared__ float sums[2][128];
    __shared__ float pl[128];
    int g = blockIdx.x;
    int t = threadIdx.x;
    int lo=0, hi=N_NODES;
    while (lo<hi){ int mid=(lo+hi)>>1; if (batch[mid] < g) lo=mid+1; else hi=mid; }
    int s = lo;
    lo = s; hi = N_NODES;
    while (lo<hi){ int mid=(lo+hi)>>1; if (batch[mid] < g+1) lo=mid+1; else hi=mid; }
    int e = lo;
    int f = t & 127, half = t >> 7;
    float sum = 0.f;
    for (int n=s+half; n<e; n+=2) sum += hacc[(size_t)n*D_HID + f];
    sums[half][f] = sum;
    __syncthreads();
    if (t < 128){
        float cnt = (float)(e - s);
        pl[t] = (sums[0][t] + sums[1][t]) / fmaxf(cnt, 1.0f);
    }
    __syncthreads();
    if (t < 128){
        float a = fcb[t];
        for (int k=0;k<128;k++) a += pl[k]*fcW[k*128 + t];
        xb[g*128 + t] = lrelu01(a);
    }
}

// ---------- final MLP ----------
__global__ __launch_bounds__(256) void k_final(const float* __restrict__ xb1, const float* __restrict__ xb2,
                      const float* __restrict__ fc1W, const float* __restrict__ fc1b,
                      const float* __restrict__ fc2W, const float* __restrict__ fc2b,
                      const float* __restrict__ outW, const float* __restrict__ outb,
                      float* __restrict__ out){
    __shared__ float xc[256], y1[256], y2[64];
    int g = blockIdx.x, t = threadIdx.x;
    xc[t] = (t < 128) ? xb1[g*128 + t] : xb2[g*128 + (t-128)];
    __syncthreads();
    float a = fc1b[t];
    for (int k=0;k<256;k++) a += xc[k]*fc1W[k*256 + t];
    y1[t] = lrelu01(a);
    __syncthreads();
    if (t < 64){
        float a2 = fc2b[t];
        for (int k=0;k<256;k++) a2 += y1[k]*fc2W[k*64 + t];
        y2[t] = lrelu01(a2);
    }
    __syncthreads();
    if (t == 0){
        float z = outb[0];
        for (int k=0;k<64;k++) z += y2[k]*outW[k];
        out[g] = 1.f/(1.f + expf(-z));
    }
}

extern "C" void kernel_launch(void* const* d_in, const int* in_sizes, int n_in,
                              void* d_out, int out_size, void* d_ws, size_t ws_size,
                              hipStream_t stream){
    const float* xs[2]      = {(const float*)d_in[0],  (const float*)d_in[5]};
    const int*   eis[2][3]  = {{(const int*)d_in[1],(const int*)d_in[2],(const int*)d_in[3]},
                               {(const int*)d_in[6],(const int*)d_in[7],(const int*)d_in[8]}};
    const int*   batches[2] = {(const int*)d_in[4],  (const int*)d_in[9]};
    const float* Wd[2]      = {(const float*)d_in[10],(const float*)d_in[16]};
    const float* avs[2][2]  = {{(const float*)d_in[11],(const float*)d_in[12]},
                               {(const float*)d_in[17],(const float*)d_in[18]}};
    const float* bvs[2]     = {(const float*)d_in[13],(const float*)d_in[19]};
    const float* pWs[2]     = {(const float*)d_in[14],(const float*)d_in[20]};
    const float* pbs[2]     = {(const float*)d_in[15],(const float*)d_in[21]};
    const float* fc1W=(const float*)d_in[22], *fc1b=(const float*)d_in[23];
    const float* fc2W=(const float*)d_in[24], *fc2b=(const float*)d_in[25];
    const float* outW=(const float*)d_in[26], *outb=(const float*)d_in[27];
    float* out = (float*)d_out;

    char* ws = (char*)d_ws;
    size_t o = 0;
    auto alloc = [&](size_t bytes)->char*{ char* p = ws + o; o += (bytes + 511) & ~(size_t)511; return p; };
    ushort* Hb    = (ushort*)alloc((size_t)N_NODES*D_HID*2);
    float*  hacc  = (float*) alloc((size_t)N_NODES*D_HID*4);
    float*  als   = (float*) alloc((size_t)N_NODES*4);
    float*  ald   = (float*) alloc((size_t)N_NODES*4);
    int*    offs3 = (int*)   alloc((size_t)(NT3+1)*4);
    int*    esrc3 = (int*)   alloc((size_t)3*N_EDGES*4);
    int*    gcur  = (int*)   alloc((size_t)NB*4);
    int*    bktb  = (int*)   alloc((size_t)NB*4);
    uint2*  pairs = (uint2*) alloc((size_t)NB*CAP*8);
    ushort* Wt    = (ushort*)alloc((size_t)D_HID*F_IN*2);
    float*  xb1   = (float*) alloc((size_t)N_GRAPH*D_HID*4);
    float*  xb2   = (float*) alloc((size_t)N_GRAPH*D_HID*4);

    const int nbin = (3*N_EDGES + EPB - 1) / EPB;

    for (int br=0; br<2; br++){
        float* xb = br ? xb2 : xb1;
        k_cast_wt<<<(D_HID*F_IN)/256, 256, 0, stream>>>(Wd[br], Wt);
        k_gemm<<<(N_NODES+BM-1)/BM, 256, 0, stream>>>(xs[br], Wt, Hb, N_NODES);
        k_al<<<(N_NODES+3)/4, 256, 0, stream>>>((const uint*)Hb, avs[br][0], avs[br][1], als, ald);
        k_zero    <<<(NB+255)/256, 256, 0, stream>>>(gcur, NB);
        k_bin     <<<nbin, 256, 0, stream>>>(eis[br][0], eis[br][1], eis[br][2], gcur, pairs);
        k_bktscan <<<1, 512, 0, stream>>>(gcur, bktb, offs3);
        k_localcsr<<<NB, 256, 0, stream>>>(gcur, bktb, pairs, offs3, esrc3);
        k_gat3    <<<(N_NODES+3)/4, 256, 0, stream>>>(offs3, esrc3, als, ald, (const uint*)Hb, bvs[br], hacc);
        k_pool_fc <<<N_GRAPH, 256, 0, stream>>>(hacc, batches[br], pWs[br], pbs[br], xb);
    }
    k_final<<<N_GRAPH, 256, 0, stream>>>(xb1, xb2, fc1W, fc1b, fc2W, fc2b, outW, outb, out);
}

// Round 4
// 568.281 us; speedup vs baseline: 3.1345x; 1.0019x over previous
//
#include <hip/hip_runtime.h>
#include <hip/hip_bf16.h>
#include <math.h>

#define N_NODES 50000
#define N_EDGES 800000
#define N_GRAPH 128
#define F_IN    1024
#define D_HID   128
#define NT3     (3*N_NODES)

// bucketed CSR build
#define NPB_SH  9
#define NPB     512
#define NB      ((NT3 + NPB - 1) / NPB)   // 293
#define CAP     10240
#define EPB     4096

typedef __bf16 bf16x8 __attribute__((ext_vector_type(8)));
typedef float  f32x4  __attribute__((ext_vector_type(4)));

__device__ __forceinline__ float lrelu01(float x){ return x > 0.f ? x : 0.01f*x; }
__device__ __forceinline__ float lrelu02(float x){ return x > 0.f ? x : 0.2f*x; }
__device__ __forceinline__ ushort f2bf(float v){
    __hip_bfloat16 hb = __float2bfloat16(v);
    return *reinterpret_cast<ushort*>(&hb);
}
__device__ __forceinline__ float2 bfu2(uint u){
    union { uint i; float f; } a, b;
    a.i = u << 16; b.i = u & 0xFFFF0000u;
    return make_float2(a.f, b.f);
}
__device__ __forceinline__ void fma8(uint4 u, float w, float* acc){
    float2 a = bfu2(u.x), b = bfu2(u.y), c = bfu2(u.z), d = bfu2(u.w);
    acc[0] += w*a.x; acc[1] += w*a.y; acc[2] += w*b.x; acc[3] += w*b.y;
    acc[4] += w*c.x; acc[5] += w*c.y; acc[6] += w*d.x; acc[7] += w*d.y;
}

// ---------- W [1024][128] f32 -> Wt [128][1024] bf16 ----------
__global__ void k_cast_wt(const float* __restrict__ W, ushort* __restrict__ Wt){
    int t = blockIdx.x*256 + threadIdx.x;
    int n = t >> 10, k = t & 1023;
    Wt[t] = f2bf(W[k*D_HID + n]);
}

// ---------- GEMM: Hb[M][128](bf16) = x[M][1024] @ W ----------
#define BM  64
#define BK  64
#define LDP 72

__global__ __launch_bounds__(256) void k_gemm(const float* __restrict__ X,
                                              const ushort* __restrict__ Wt,
                                              ushort* __restrict__ Hb, int M){
    __shared__ ushort As[BM*LDP];
    __shared__ ushort Bs[D_HID*LDP];
    int tid  = threadIdx.x;
    int m0   = blockIdx.x * BM;
    int lane = tid & 63;
    int wave = tid >> 6;
    int l15 = lane & 15, l4 = lane >> 4;
    int wcol = wave * 32;

    float4 pa[4];
    uint4  pb[4];

    auto loadA = [&](int kt){
        #pragma unroll
        for (int i=0;i<4;i++){
            int q = tid + i*256; int row = q >> 4; int kq = (q & 15) << 2;
            int gr = m0 + row;
            pa[i] = (gr < M) ? *reinterpret_cast<const float4*>(X + (size_t)gr*F_IN + kt + kq)
                             : make_float4(0.f,0.f,0.f,0.f);
        }
    };
    auto loadB = [&](int kt){
        #pragma unroll
        for (int i=0;i<4;i++){
            int q = tid + i*256; int row = q >> 3; int ck = q & 7;
            pb[i] = *reinterpret_cast<const uint4*>(Wt + row*F_IN + kt + ck*8);
        }
    };
    auto stage = [&](){
        #pragma unroll
        for (int i=0;i<4;i++){
            int q = tid + i*256; int row = q >> 4; int kq = (q & 15) << 2;
            ushort4 b; b.x=f2bf(pa[i].x); b.y=f2bf(pa[i].y); b.z=f2bf(pa[i].z); b.w=f2bf(pa[i].w);
            *reinterpret_cast<ushort4*>(&As[row*LDP + kq]) = b;
        }
        #pragma unroll
        for (int i=0;i<4;i++){
            int q = tid + i*256; int row = q >> 3; int ck = q & 7;
            *reinterpret_cast<uint2*>(&Bs[row*LDP + ck*8])     = make_uint2(pb[i].x, pb[i].y);
            *reinterpret_cast<uint2*>(&Bs[row*LDP + ck*8 + 4]) = make_uint2(pb[i].z, pb[i].w);
        }
    };

    f32x4 acc[4][2];
    #pragma unroll
    for (int i=0;i<4;i++) for (int j=0;j<2;j++) acc[i][j] = (f32x4){0.f,0.f,0.f,0.f};

    loadA(0); loadB(0);
    for (int kt = 0; kt < F_IN; kt += BK) {
        stage();
        __syncthreads();
        if (kt + BK < F_IN){ loadA(kt+BK); loadB(kt+BK); }
        #pragma unroll
        for (int kk = 0; kk < BK; kk += 32) {
            bf16x8 af[4], bfr[2];
            #pragma unroll
            for (int mi=0;mi<4;mi++)
                af[mi] = *reinterpret_cast<const bf16x8*>(&As[(mi*16+l15)*LDP + kk + l4*8]);
            #pragma unroll
            for (int ni=0;ni<2;ni++)
                bfr[ni] = *reinterpret_cast<const bf16x8*>(&Bs[(wcol+ni*16+l15)*LDP + kk + l4*8]);
            #pragma unroll
            for (int mi=0;mi<4;mi++)
                #pragma unroll
                for (int ni=0;ni<2;ni++)
                    acc[mi][ni] = __builtin_amdgcn_mfma_f32_16x16x32_bf16(af[mi], bfr[ni], acc[mi][ni], 0,0,0);
        }
        __syncthreads();
    }
    #pragma unroll
    for (int mi=0;mi<4;mi++){
        #pragma unroll
        for (int jj=0;jj<4;jj++){
            int r = m0 + mi*16 + l4*4 + jj;
            if (r < M){
                #pragma unroll
                for (int ni=0;ni<2;ni++){
                    int c = wcol + ni*16 + l15;
                    Hb[(size_t)r*D_HID + c] = f2bf(acc[mi][ni][jj]);
                }
            }
        }
    }
}

// ---------- al_s/al_d from bf16 h ----------
__global__ __launch_bounds__(256) void k_al(const uint* __restrict__ Hb2,
                    const float* __restrict__ asrc, const float* __restrict__ adst,
                    float* __restrict__ als, float* __restrict__ ald){
    int lane = threadIdx.x & 63;
    int row  = blockIdx.x*4 + (threadIdx.x >> 6);
    if (row >= N_NODES) return;
    float2 v  = bfu2(Hb2[(size_t)row*64 + lane]);
    float2 as = *reinterpret_cast<const float2*>(asrc + 2*lane);
    float2 ad = *reinterpret_cast<const float2*>(adst + 2*lane);
    float ds = v.x*as.x + v.y*as.y;
    float dd = v.x*ad.x + v.y*ad.y;
    for (int o=32;o;o>>=1){ ds += __shfl_xor(ds,o); dd += __shfl_xor(dd,o); }
    if (lane==0){ als[row]=ds; ald[row]=dd; }
}

// ---------- bucketed CSR (packed: bits 16..24 = local dst, bits 0..15 = src) ----------
__global__ void k_zero(int* __restrict__ p, int n){
    int i = blockIdx.x*256 + threadIdx.x;
    if (i < n) p[i] = 0;
}

__global__ __launch_bounds__(256) void k_bin(const int* __restrict__ e1, const int* __restrict__ e2,
                                             const int* __restrict__ e3,
                                             int* __restrict__ gcur, uint* __restrict__ pairs){
    __shared__ int hist[NB];
    __shared__ int start[NB];
    int tid = threadIdx.x;
    for (int b=tid; b<NB; b+=256) hist[b]=0;
    __syncthreads();
    long base = (long)blockIdx.x * EPB;
    int  myb[16]; uint mypk[16];
    #pragma unroll
    for (int i=0;i<16;i++){
        long idx = base + i*256 + tid;
        int b = -1; uint pk = 0;
        if (idx < 3L*N_EDGES){
            int hop = (idx >= 2L*N_EDGES) ? 2 : (idx >= (long)N_EDGES) ? 1 : 0;
            int e   = (int)(idx - (long)hop*N_EDGES);
            const int* ei = (hop==0) ? e1 : (hop==1) ? e2 : e3;
            int src = ei[e];
            int vd  = hop*N_NODES + ei[N_EDGES + e];
            b   = vd >> NPB_SH;
            pk  = (uint)src | ((uint)(vd & (NPB-1)) << 16);
            atomicAdd(&hist[b], 1);
        }
        myb[i]=b; mypk[i]=pk;
    }
    __syncthreads();
    for (int b=tid; b<NB; b+=256){
        int h = hist[b];
        start[b] = (h>0) ? atomicAdd(&gcur[b], h) : 0;
    }
    __syncthreads();
    for (int b=tid; b<NB; b+=256) hist[b] = start[b];
    __syncthreads();
    #pragma unroll
    for (int i=0;i<16;i++){
        int b = myb[i];
        if (b >= 0){
            int pos = atomicAdd(&hist[b], 1);
            if (pos < CAP) pairs[(size_t)b*CAP + pos] = mypk[i];
        }
    }
}

__global__ __launch_bounds__(512) void k_bktscan(const int* __restrict__ gcur,
                                                 int* __restrict__ bktbase, int* __restrict__ offs3){
    __shared__ int s[512];
    int t = threadIdx.x;
    int v = (t < NB) ? min(gcur[t], CAP) : 0;
    s[t] = v; __syncthreads();
    for (int o=1;o<512;o<<=1){
        int u = (t>=o) ? s[t-o] : 0;
        __syncthreads(); s[t] += u; __syncthreads();
    }
    if (t < NB) bktbase[t] = s[t] - v;
    if (t == NB-1) offs3[NT3] = s[t];
}

__global__ __launch_bounds__(256) void k_localcsr(const int* __restrict__ gcur,
                                                  const int* __restrict__ bktbase,
                                                  const uint* __restrict__ pairs,
                                                  int* __restrict__ offs3, int* __restrict__ esrc){
    __shared__ int deg[NPB];
    __shared__ int cur[NPB];
    __shared__ int ss[256];
    int b = blockIdx.x, t = threadIdx.x;
    int cnt = min(gcur[b], CAP);
    deg[t]=0; deg[t+256]=0;
    __syncthreads();
    const uint* pb = pairs + (size_t)b*CAP;
    for (int i=t; i<cnt; i+=256) atomicAdd(&deg[pb[i] >> 16], 1);
    __syncthreads();
    int a0 = deg[2*t], a1 = deg[2*t+1];
    int ps = a0 + a1;
    ss[t] = ps; __syncthreads();
    for (int o=1;o<256;o<<=1){
        int u = (t>=o) ? ss[t-o] : 0;
        __syncthreads(); ss[t] += u; __syncthreads();
    }
    int ex = ss[t] - ps;
    __syncthreads();
    deg[2*t] = ex; deg[2*t+1] = ex + a0;
    cur[2*t] = ex; cur[2*t+1] = ex + a0;
    __syncthreads();
    int base = bktbase[b];
    int vd0 = b << NPB_SH;
    for (int l=t; l<NPB; l+=256){
        int vd = vd0 + l;
        if (vd < NT3) offs3[vd] = base + deg[l];
    }
    for (int i=t; i<cnt; i+=256){
        uint p = pb[i];
        int pos = atomicAdd(&cur[p >> 16], 1);
        esrc[base + pos] = (int)(p & 0xFFFFu);
    }
}

// ---------- GAT aggregate: 4x16-lane groups, uint4 rows, all 3 hops ----------
__global__ __launch_bounds__(256) void k_gat3(const int* __restrict__ offs, const int* __restrict__ esrc,
                     const float* __restrict__ als, const float* __restrict__ ald,
                     const uint4* __restrict__ H4, const float* __restrict__ bvec,
                     float* __restrict__ hacc){
    int lane = threadIdx.x & 63;
    int d = blockIdx.x*4 + (threadIdx.x >> 6);
    if (d >= N_NODES) return;
    int g  = lane >> 4;
    int fl = lane & 15;
    float aldd  = ald[d];
    float eself = lrelu02(als[d] + aldd);
    float exs   = expf(fminf(eself, 50.f));
    uint4 hs = H4[(size_t)d*16 + fl];
    float hself[8];
    { float2 a=bfu2(hs.x),b=bfu2(hs.y),c=bfu2(hs.z),dd2=bfu2(hs.w);
      hself[0]=a.x;hself[1]=a.y;hself[2]=b.x;hself[3]=b.y;
      hself[4]=c.x;hself[5]=c.y;hself[6]=dd2.x;hself[7]=dd2.y; }
    float bvv[8];
    #pragma unroll
    for (int k=0;k<8;k++) bvv[k] = bvec[fl*8+k];
    float tot[8] = {0.f,0.f,0.f,0.f,0.f,0.f,0.f,0.f};

    for (int hop=0; hop<3; hop++){
        int s0 = offs[hop*N_NODES + d];
        int s1 = offs[hop*N_NODES + d + 1];
        int deg = s1 - s0;
        float acc[8];
        #pragma unroll
        for (int k=0;k<8;k++) acc[k] = (g==0) ? exs*hself[k] : 0.f;
        float es = 0.f;
        for (int base=0; base<deg; base+=64){
            int j = base + lane;
            int s = 0; float ex = 0.f;
            if (j < deg){
                s = esrc[s0 + j];
                ex = expf(fminf(lrelu02(als[s] + aldd), 50.f));
            }
            es += ex;
            int cnt = min(64, deg - base);
            for (int i = g; i < cnt; i += 4){
                int   sj = __shfl(s,  i);
                float ej = __shfl(ex, i);
                uint4 hv = H4[(size_t)sj*16 + fl];
                fma8(hv, ej, acc);
            }
        }
        for (int o=32;o;o>>=1) es += __shfl_xor(es,o);
        #pragma unroll
        for (int k=0;k<8;k++){
            acc[k] += __shfl_xor(acc[k], 16);
            acc[k] += __shfl_xor(acc[k], 32);
        }
        float inv = 1.f / (es + exs);
        #pragma unroll
        for (int k=0;k<8;k++) tot[k] += lrelu01(acc[k]*inv + bvv[k]);
    }
    if (g == 0){
        float4 w0 = make_float4(tot[0],tot[1],tot[2],tot[3]);
        float4 w1 = make_float4(tot[4],tot[5],tot[6],tot[7]);
        *reinterpret_cast<float4*>(hacc + (size_t)d*D_HID + fl*8)     = w0;
        *reinterpret_cast<float4*>(hacc + (size_t)d*D_HID + fl*8 + 4) = w1;
    }
}

// ---------- mean-pool per graph + branch FC ----------
__global__ __launch_bounds__(256) void k_pool_fc(const float* __restrict__ hacc,
                    const int* __restrict__ batch,
                    const float* __restrict__ fcW, const float* __restrict__ fcb,
                    float* __restrict__ xb){
    __shared__ float sums[2][128];
    __shared__ float pl[128];
    int g = blockIdx.x;
    int t = threadIdx.x;
    int lo=0, hi=N_NODES;
    while (lo<hi){ int mid=(lo+hi)>>1; if (batch[mid] < g) lo=mid+1; else hi=mid; }
    int s = lo;
    lo = s; hi = N_NODES;
    while (lo<hi){ int mid=(lo+hi)>>1; if (batch[mid] < g+1) lo=mid+1; else hi=mid; }
    int e = lo;
    int f = t & 127, half = t >> 7;
    float sum = 0.f;
    for (int n=s+half; n<e; n+=2) sum += hacc[(size_t)n*D_HID + f];
    sums[half][f] = sum;
    __syncthreads();
    if (t < 128){
        float cnt = (float)(e - s);
        pl[t] = (sums[0][t] + sums[1][t]) / fmaxf(cnt, 1.0f);
    }
    __syncthreads();
    if (t < 128){
        float a = fcb[t];
        for (int k=0;k<128;k++) a += pl[k]*fcW[k*128 + t];
        xb[g*128 + t] = lrelu01(a);
    }
}

// ---------- final MLP ----------
__global__ __launch_bounds__(256) void k_final(const float* __restrict__ xb1, const float* __restrict__ xb2,
                      const float* __restrict__ fc1W, const float* __restrict__ fc1b,
                      const float* __restrict__ fc2W, const float* __restrict__ fc2b,
                      const float* __restrict__ outW, const float* __restrict__ outb,
                      float* __restrict__ out){
    __shared__ float xc[256], y1[256], y2[64];
    int g = blockIdx.x, t = threadIdx.x;
    xc[t] = (t < 128) ? xb1[g*128 + t] : xb2[g*128 + (t-128)];
    __syncthreads();
    float a = fc1b[t];
    for (int k=0;k<256;k++) a += xc[k]*fc1W[k*256 + t];
    y1[t] = lrelu01(a);
    __syncthreads();
    if (t < 64){
        float a2 = fc2b[t];
        for (int k=0;k<256;k++) a2 += y1[k]*fc2W[k*64 + t];
        y2[t] = lrelu01(a2);
    }
    __syncthreads();
    if (t == 0){
        float z = outb[0];
        for (int k=0;k<64;k++) z += y2[k]*outW[k];
        out[g] = 1.f/(1.f + expf(-z));
    }
}

extern "C" void kernel_launch(void* const* d_in, const int* in_sizes, int n_in,
                              void* d_out, int out_size, void* d_ws, size_t ws_size,
                              hipStream_t stream){
    const float* xs[2]      = {(const float*)d_in[0],  (const float*)d_in[5]};
    const int*   eis[2][3]  = {{(const int*)d_in[1],(const int*)d_in[2],(const int*)d_in[3]},
                               {(const int*)d_in[6],(const int*)d_in[7],(const int*)d_in[8]}};
    const int*   batches[2] = {(const int*)d_in[4],  (const int*)d_in[9]};
    const float* Wd[2]      = {(const float*)d_in[10],(const float*)d_in[16]};
    const float* avs[2][2]  = {{(const float*)d_in[11],(const float*)d_in[12]},
                               {(const float*)d_in[17],(const float*)d_in[18]}};
    const float* bvs[2]     = {(const float*)d_in[13],(const float*)d_in[19]};
    const float* pWs[2]     = {(const float*)d_in[14],(const float*)d_in[20]};
    const float* pbs[2]     = {(const float*)d_in[15],(const float*)d_in[21]};
    const float* fc1W=(const float*)d_in[22], *fc1b=(const float*)d_in[23];
    const float* fc2W=(const float*)d_in[24], *fc2b=(const float*)d_in[25];
    const float* outW=(const float*)d_in[26], *outb=(const float*)d_in[27];
    float* out = (float*)d_out;

    char* ws = (char*)d_ws;
    size_t o = 0;
    auto alloc = [&](size_t bytes)->char*{ char* p = ws + o; o += (bytes + 511) & ~(size_t)511; return p; };
    ushort* Hb    = (ushort*)alloc((size_t)N_NODES*D_HID*2);
    float*  hacc  = (float*) alloc((size_t)N_NODES*D_HID*4);
    float*  als   = (float*) alloc((size_t)N_NODES*4);
    float*  ald   = (float*) alloc((size_t)N_NODES*4);
    int*    offs3 = (int*)   alloc((size_t)(NT3+1)*4);
    int*    esrc3 = (int*)   alloc((size_t)3*N_EDGES*4);
    int*    gcur  = (int*)   alloc((size_t)NB*4);
    int*    bktb  = (int*)   alloc((size_t)NB*4);
    uint*   pairs = (uint*)  alloc((size_t)NB*CAP*4);
    ushort* Wt    = (ushort*)alloc((size_t)D_HID*F_IN*2);
    float*  xb1   = (float*) alloc((size_t)N_GRAPH*D_HID*4);
    float*  xb2   = (float*) alloc((size_t)N_GRAPH*D_HID*4);

    const int nbin = (3*N_EDGES + EPB - 1) / EPB;

    for (int br=0; br<2; br++){
        float* xb = br ? xb2 : xb1;
        k_cast_wt<<<(D_HID*F_IN)/256, 256, 0, stream>>>(Wd[br], Wt);
        k_gemm<<<(N_NODES+BM-1)/BM, 256, 0, stream>>>(xs[br], Wt, Hb, N_NODES);
        k_al<<<(N_NODES+3)/4, 256, 0, stream>>>((const uint*)Hb, avs[br][0], avs[br][1], als, ald);
        k_zero    <<<(NB+255)/256, 256, 0, stream>>>(gcur, NB);
        k_bin     <<<nbin, 256, 0, stream>>>(eis[br][0], eis[br][1], eis[br][2], gcur, pairs);
        k_bktscan <<<1, 512, 0, stream>>>(gcur, bktb, offs3);
        k_localcsr<<<NB, 256, 0, stream>>>(gcur, bktb, pairs, offs3, esrc3);
        k_gat3    <<<(N_NODES+3)/4, 256, 0, stream>>>(offs3, esrc3, als, ald, (const uint4*)Hb, bvs[br], hacc);
        k_pool_fc <<<N_GRAPH, 256, 0, stream>>>(hacc, batches[br], pWs[br], pbs[br], xb);
    }
    k_final<<<N_GRAPH, 256, 0, stream>>>(xb1, xb2, fc1W, fc1b, fc2W, fc2b, outW, outb, out);
}

// Round 5
// 445.170 us; speedup vs baseline: 4.0014x; 1.2765x over previous
//
#include <hip/hip_runtime.h>
#include <hip/hip_bf16.h>
#include <math.h>

#define N_NODES 50000
#define N_EDGES 800000
#define N_GRAPH 128
#define F_IN    1024
#define D_HID   128
#define NT3     (3*N_NODES)

// bucketed CSR build
#define NPB_SH  9
#define NPB     512
#define NB      ((NT3 + NPB - 1) / NPB)   // 293
#define CAP     10240
#define EPB     4096
#define NBIN_PB ((3*N_EDGES + EPB - 1) / EPB)   // 586 blocks per branch

typedef __bf16 bf16x8 __attribute__((ext_vector_type(8)));
typedef float  f32x4  __attribute__((ext_vector_type(4)));

__device__ __forceinline__ float lrelu01(float x){ return x > 0.f ? x : 0.01f*x; }
__device__ __forceinline__ float lrelu02(float x){ return x > 0.f ? x : 0.2f*x; }
__device__ __forceinline__ ushort f2bf(float v){
    __hip_bfloat16 hb = __float2bfloat16(v);
    return *reinterpret_cast<ushort*>(&hb);
}
__device__ __forceinline__ float2 bfu2(uint u){
    union { uint i; float f; } a, b;
    a.i = u << 16; b.i = u & 0xFFFF0000u;
    return make_float2(a.f, b.f);
}
__device__ __forceinline__ void fma8(uint4 u, float w, float* acc){
    float2 a = bfu2(u.x), b = bfu2(u.y), c = bfu2(u.z), d = bfu2(u.w);
    acc[0] += w*a.x; acc[1] += w*a.y; acc[2] += w*b.x; acc[3] += w*b.y;
    acc[4] += w*c.x; acc[5] += w*c.y; acc[6] += w*d.x; acc[7] += w*d.y;
}

// ---------- prep: cast both W's to Wt[2][128][1024] bf16 + zero gcur ----------
__global__ void k_prep(const float* __restrict__ W0, const float* __restrict__ W1,
                       ushort* __restrict__ Wt, int* __restrict__ gcur){
    int b = blockIdx.x, t = threadIdx.x;
    if (b < 1024){
        int idx = b*256 + t;              // 0 .. 262143
        int br  = idx >> 17;              // 131072 per branch
        int r   = idx & 131071;
        int n = r >> 10, k = r & 1023;
        const float* W = br ? W1 : W0;
        Wt[idx] = f2bf(W[k*D_HID + n]);
    } else {
        for (int i=t; i<2*NB; i+=256) gcur[i] = 0;
    }
}

// ---------- GEMM both branches + fused al_s/al_d epilogue ----------
#define BM  64
#define BK  64
#define LDP 72

__global__ __launch_bounds__(256) void k_gemm(const float* __restrict__ X0, const float* __restrict__ X1,
                                              const ushort* __restrict__ Wt,
                                              const float* __restrict__ as0, const float* __restrict__ ad0,
                                              const float* __restrict__ as1, const float* __restrict__ ad1,
                                              ushort* __restrict__ Hb,
                                              float* __restrict__ als, float* __restrict__ ald){
    __shared__ ushort As[BM*LDP];
    __shared__ ushort Bs[D_HID*LDP];
    __shared__ float alp[4][2][64];
    int br = blockIdx.y;
    const float*  X   = br ? X1 : X0;
    const float*  asr = br ? as1 : as0;
    const float*  adr = br ? ad1 : ad0;
    const ushort* Wtb = Wt + (size_t)br*D_HID*F_IN;
    ushort*       Hbb = Hb + (size_t)br*N_NODES*D_HID;

    int tid  = threadIdx.x;
    int m0   = blockIdx.x * BM;
    int lane = tid & 63;
    int wave = tid >> 6;
    int l15 = lane & 15, l4 = lane >> 4;
    int wcol = wave * 32;

    float4 pa[4];
    uint4  pb[4];

    auto loadA = [&](int kt){
        #pragma unroll
        for (int i=0;i<4;i++){
            int q = tid + i*256; int row = q >> 4; int kq = (q & 15) << 2;
            int gr = m0 + row;
            pa[i] = (gr < N_NODES) ? *reinterpret_cast<const float4*>(X + (size_t)gr*F_IN + kt + kq)
                                   : make_float4(0.f,0.f,0.f,0.f);
        }
    };
    auto loadB = [&](int kt){
        #pragma unroll
        for (int i=0;i<4;i++){
            int q = tid + i*256; int row = q >> 3; int ck = q & 7;
            pb[i] = *reinterpret_cast<const uint4*>(Wtb + row*F_IN + kt + ck*8);
        }
    };
    auto stage = [&](){
        #pragma unroll
        for (int i=0;i<4;i++){
            int q = tid + i*256; int row = q >> 4; int kq = (q & 15) << 2;
            ushort4 b; b.x=f2bf(pa[i].x); b.y=f2bf(pa[i].y); b.z=f2bf(pa[i].z); b.w=f2bf(pa[i].w);
            *reinterpret_cast<ushort4*>(&As[row*LDP + kq]) = b;
        }
        #pragma unroll
        for (int i=0;i<4;i++){
            int q = tid + i*256; int row = q >> 3; int ck = q & 7;
            *reinterpret_cast<uint2*>(&Bs[row*LDP + ck*8])     = make_uint2(pb[i].x, pb[i].y);
            *reinterpret_cast<uint2*>(&Bs[row*LDP + ck*8 + 4]) = make_uint2(pb[i].z, pb[i].w);
        }
    };

    f32x4 acc[4][2];
    #pragma unroll
    for (int i=0;i<4;i++) for (int j=0;j<2;j++) acc[i][j] = (f32x4){0.f,0.f,0.f,0.f};

    loadA(0); loadB(0);
    for (int kt = 0; kt < F_IN; kt += BK) {
        stage();
        __syncthreads();
        if (kt + BK < F_IN){ loadA(kt+BK); loadB(kt+BK); }
        #pragma unroll
        for (int kk = 0; kk < BK; kk += 32) {
            bf16x8 af[4], bfr[2];
            #pragma unroll
            for (int mi=0;mi<4;mi++)
                af[mi] = *reinterpret_cast<const bf16x8*>(&As[(mi*16+l15)*LDP + kk + l4*8]);
            #pragma unroll
            for (int ni=0;ni<2;ni++)
                bfr[ni] = *reinterpret_cast<const bf16x8*>(&Bs[(wcol+ni*16+l15)*LDP + kk + l4*8]);
            #pragma unroll
            for (int mi=0;mi<4;mi++)
                #pragma unroll
                for (int ni=0;ni<2;ni++)
                    acc[mi][ni] = __builtin_amdgcn_mfma_f32_16x16x32_bf16(af[mi], bfr[ni], acc[mi][ni], 0,0,0);
        }
        __syncthreads();
    }

    // epilogue: Hb write + fused al_s/al_d
    float asv[2], adv[2];
    #pragma unroll
    for (int ni=0;ni<2;ni++){
        int c = wcol + ni*16 + l15;
        asv[ni] = asr[c]; adv[ni] = adr[c];
    }
    #pragma unroll
    for (int mi=0;mi<4;mi++){
        #pragma unroll
        for (int jj=0;jj<4;jj++){
            int rrel = mi*16 + l4*4 + jj;
            int r = m0 + rrel;
            float ps = 0.f, pd = 0.f;
            #pragma unroll
            for (int ni=0;ni<2;ni++){
                float v = acc[mi][ni][jj];
                ps += v*asv[ni]; pd += v*adv[ni];
                if (r < N_NODES){
                    int c = wcol + ni*16 + l15;
                    Hbb[(size_t)r*D_HID + c] = f2bf(v);
                }
            }
            #pragma unroll
            for (int o=1;o<16;o<<=1){ ps += __shfl_xor(ps,o); pd += __shfl_xor(pd,o); }
            if (l15 == 0){ alp[wave][0][rrel] = ps; alp[wave][1][rrel] = pd; }
        }
    }
    __syncthreads();
    if (tid < 64){
        int r = m0 + tid;
        if (r < N_NODES){
            float s_ = alp[0][0][tid]+alp[1][0][tid]+alp[2][0][tid]+alp[3][0][tid];
            float d_ = alp[0][1][tid]+alp[1][1][tid]+alp[2][1][tid]+alp[3][1][tid];
            als[br*N_NODES + r] = s_;
            ald[br*N_NODES + r] = d_;
        }
    }
}

// ---------- bucketed CSR: bin (both branches) ----------
__global__ __launch_bounds__(256) void k_bin(const int* __restrict__ e10, const int* __restrict__ e20,
                                             const int* __restrict__ e30,
                                             const int* __restrict__ e11, const int* __restrict__ e21,
                                             const int* __restrict__ e31,
                                             int* __restrict__ gcur, uint* __restrict__ pairs){
    __shared__ int hist[NB];
    __shared__ int start[NB];
    int blk = blockIdx.x;
    int br    = blk / NBIN_PB;
    int chunk = blk - br*NBIN_PB;
    int tid = threadIdx.x;
    for (int b=tid; b<NB; b+=256) hist[b]=0;
    __syncthreads();
    long base = (long)chunk * EPB;
    int  myb[16]; uint mypk[16];
    #pragma unroll
    for (int i=0;i<16;i++){
        long idx = base + i*256 + tid;
        int b = -1; uint pk = 0;
        if (idx < 3L*N_EDGES){
            int hop = (idx >= 2L*N_EDGES) ? 2 : (idx >= (long)N_EDGES) ? 1 : 0;
            int e   = (int)(idx - (long)hop*N_EDGES);
            const int* ei = (br==0) ? ((hop==0)?e10:(hop==1)?e20:e30)
                                    : ((hop==0)?e11:(hop==1)?e21:e31);
            int src = ei[e];
            int vd  = hop*N_NODES + ei[N_EDGES + e];
            b   = vd >> NPB_SH;
            pk  = (uint)src | ((uint)(vd & (NPB-1)) << 16);
            atomicAdd(&hist[b], 1);
        }
        myb[i]=b; mypk[i]=pk;
    }
    __syncthreads();
    for (int b=tid; b<NB; b+=256){
        int h = hist[b];
        start[b] = (h>0) ? atomicAdd(&gcur[br*NB + b], h) : 0;
    }
    __syncthreads();
    for (int b=tid; b<NB; b+=256) hist[b] = start[b];
    __syncthreads();
    #pragma unroll
    for (int i=0;i<16;i++){
        int b = myb[i];
        if (b >= 0){
            int pos = atomicAdd(&hist[b], 1);
            if (pos < CAP) pairs[((size_t)(br*NB + b))*CAP + pos] = mypk[i];
        }
    }
}

// ---------- localcsr: per-block inline bucket prefix + local scan/fill ----------
__global__ __launch_bounds__(256) void k_localcsr(const int* __restrict__ gcur,
                                                  const uint* __restrict__ pairs,
                                                  int* __restrict__ offs3, int* __restrict__ esrc){
    __shared__ int sc[512];
    __shared__ int deg[NPB];
    __shared__ int cur[NPB];
    __shared__ int ss[256];
    int gb = blockIdx.x;
    int br = gb / NB, bb = gb - br*NB;
    int t = threadIdx.x;
    // capped counts for this branch, then 512-wide inclusive scan
    sc[t]     = (t < NB)       ? min(gcur[br*NB + t], CAP) : 0;
    sc[t+256] = (t+256 < NB)   ? min(gcur[br*NB + t+256], CAP) : 0;
    __syncthreads();
    for (int o=1;o<512;o<<=1){
        int v0 = (t>=o)     ? sc[t-o]     : 0;
        int v1 = (t+256>=o) ? sc[t+256-o] : 0;
        __syncthreads();
        sc[t] += v0; sc[t+256] += v1;
        __syncthreads();
    }
    int base = (bb==0) ? 0 : sc[bb-1];
    int cnt  = sc[bb] - base;
    int* offsb = offs3 + (size_t)br*(NT3+1);
    if (bb == NB-1 && t == 0) offsb[NT3] = sc[NB-1];

    deg[t]=0; deg[t+256]=0;
    __syncthreads();
    const uint* pbuf = pairs + ((size_t)(br*NB + bb))*CAP;
    for (int i=t; i<cnt; i+=256) atomicAdd(&deg[pbuf[i] >> 16], 1);
    __syncthreads();
    int a0 = deg[2*t], a1 = deg[2*t+1];
    int ps = a0 + a1;
    ss[t] = ps; __syncthreads();
    for (int o=1;o<256;o<<=1){
        int u = (t>=o) ? ss[t-o] : 0;
        __syncthreads(); ss[t] += u; __syncthreads();
    }
    int ex = ss[t] - ps;
    __syncthreads();
    deg[2*t] = ex; deg[2*t+1] = ex + a0;
    cur[2*t] = ex; cur[2*t+1] = ex + a0;
    __syncthreads();
    int vd0 = bb << NPB_SH;
    for (int l=t; l<NPB; l+=256){
        int vd = vd0 + l;
        if (vd < NT3) offsb[vd] = base + deg[l];
    }
    int* esrcb = esrc + (size_t)br*3*N_EDGES;
    for (int i=t; i<cnt; i+=256){
        uint p = pbuf[i];
        int pos = atomicAdd(&cur[p >> 16], 1);
        esrcb[base + pos] = (int)(p & 0xFFFFu);
    }
}

// ---------- GAT aggregate: both branches, 4x16-lane groups ----------
__global__ __launch_bounds__(256) void k_gat3(const int* __restrict__ offs3, const int* __restrict__ esrc3,
                     const float* __restrict__ als, const float* __restrict__ ald,
                     const uint4* __restrict__ H4,
                     const float* __restrict__ bv0, const float* __restrict__ bv1,
                     float* __restrict__ hacc){
    int br = blockIdx.y;
    const int*   offs = offs3 + (size_t)br*(NT3+1);
    const int*   esrc = esrc3 + (size_t)br*3*N_EDGES;
    const float* alsb = als + br*N_NODES;
    const float* aldb = ald + br*N_NODES;
    const uint4* H4b  = H4 + (size_t)br*N_NODES*16;
    const float* bvec = br ? bv1 : bv0;
    float*       hb   = hacc + (size_t)br*N_NODES*D_HID;

    int lane = threadIdx.x & 63;
    int d = blockIdx.x*4 + (threadIdx.x >> 6);
    if (d >= N_NODES) return;
    int g  = lane >> 4;
    int fl = lane & 15;
    float aldd  = aldb[d];
    float eself = lrelu02(alsb[d] + aldd);
    float exs   = expf(fminf(eself, 50.f));
    uint4 hs = H4b[(size_t)d*16 + fl];
    float hself[8];
    { float2 a=bfu2(hs.x),b=bfu2(hs.y),c=bfu2(hs.z),dd2=bfu2(hs.w);
      hself[0]=a.x;hself[1]=a.y;hself[2]=b.x;hself[3]=b.y;
      hself[4]=c.x;hself[5]=c.y;hself[6]=dd2.x;hself[7]=dd2.y; }
    float bvv[8];
    #pragma unroll
    for (int k=0;k<8;k++) bvv[k] = bvec[fl*8+k];
    float tot[8] = {0.f,0.f,0.f,0.f,0.f,0.f,0.f,0.f};

    for (int hop=0; hop<3; hop++){
        int s0 = offs[hop*N_NODES + d];
        int s1 = offs[hop*N_NODES + d + 1];
        int deg = s1 - s0;
        float acc[8];
        #pragma unroll
        for (int k=0;k<8;k++) acc[k] = (g==0) ? exs*hself[k] : 0.f;
        float es = 0.f;
        for (int base=0; base<deg; base+=64){
            int j = base + lane;
            int s = 0; float ex = 0.f;
            if (j < deg){
                s = esrc[s0 + j];
                ex = expf(fminf(lrelu02(alsb[s] + aldd), 50.f));
            }
            es += ex;
            int cnt = min(64, deg - base);
            for (int i = g; i < cnt; i += 4){
                int   sj = __shfl(s,  i);
                float ej = __shfl(ex, i);
                uint4 hv = H4b[(size_t)sj*16 + fl];
                fma8(hv, ej, acc);
            }
        }
        for (int o=32;o;o>>=1) es += __shfl_xor(es,o);
        #pragma unroll
        for (int k=0;k<8;k++){
            acc[k] += __shfl_xor(acc[k], 16);
            acc[k] += __shfl_xor(acc[k], 32);
        }
        float inv = 1.f / (es + exs);
        #pragma unroll
        for (int k=0;k<8;k++) tot[k] += lrelu01(acc[k]*inv + bvv[k]);
    }
    if (g == 0){
        float4 w0 = make_float4(tot[0],tot[1],tot[2],tot[3]);
        float4 w1 = make_float4(tot[4],tot[5],tot[6],tot[7]);
        *reinterpret_cast<float4*>(hb + (size_t)d*D_HID + fl*8)     = w0;
        *reinterpret_cast<float4*>(hb + (size_t)d*D_HID + fl*8 + 4) = w1;
    }
}

// ---------- mean-pool per graph + branch FC (both branches) ----------
__global__ __launch_bounds__(256) void k_pool_fc(const float* __restrict__ hacc,
                    const int* __restrict__ b0, const int* __restrict__ b1,
                    const float* __restrict__ pW0, const float* __restrict__ pb0,
                    const float* __restrict__ pW1, const float* __restrict__ pb1,
                    float* __restrict__ xb){
    __shared__ float sums[2][128];
    __shared__ float pl[128];
    int br = blockIdx.y;
    const float* hb   = hacc + (size_t)br*N_NODES*D_HID;
    const int*   batch= br ? b1 : b0;
    const float* fcW  = br ? pW1 : pW0;
    const float* fcb  = br ? pb1 : pb0;
    int g = blockIdx.x;
    int t = threadIdx.x;
    int lo=0, hi=N_NODES;
    while (lo<hi){ int mid=(lo+hi)>>1; if (batch[mid] < g) lo=mid+1; else hi=mid; }
    int s = lo;
    lo = s; hi = N_NODES;
    while (lo<hi){ int mid=(lo+hi)>>1; if (batch[mid] < g+1) lo=mid+1; else hi=mid; }
    int e = lo;
    int f = t & 127, half = t >> 7;
    float sum = 0.f;
    for (int n=s+half; n<e; n+=2) sum += hb[(size_t)n*D_HID + f];
    sums[half][f] = sum;
    __syncthreads();
    if (t < 128){
        float cnt = (float)(e - s);
        pl[t] = (sums[0][t] + sums[1][t]) / fmaxf(cnt, 1.0f);
    }
    __syncthreads();
    if (t < 128){
        float a = fcb[t];
        for (int k=0;k<128;k++) a += pl[k]*fcW[k*128 + t];
        xb[(br*N_GRAPH + g)*128 + t] = lrelu01(a);
    }
}

// ---------- final MLP ----------
__global__ __launch_bounds__(256) void k_final(const float* __restrict__ xb,
                      const float* __restrict__ fc1W, const float* __restrict__ fc1b,
                      const float* __restrict__ fc2W, const float* __restrict__ fc2b,
                      const float* __restrict__ outW, const float* __restrict__ outb,
                      float* __restrict__ out){
    __shared__ float xc[256], y1[256], y2[64];
    int g = blockIdx.x, t = threadIdx.x;
    xc[t] = (t < 128) ? xb[g*128 + t] : xb[(N_GRAPH + g)*128 + (t-128)];
    __syncthreads();
    float a = fc1b[t];
    for (int k=0;k<256;k++) a += xc[k]*fc1W[k*256 + t];
    y1[t] = lrelu01(a);
    __syncthreads();
    if (t < 64){
        float a2 = fc2b[t];
        for (int k=0;k<256;k++) a2 += y1[k]*fc2W[k*64 + t];
        y2[t] = lrelu01(a2);
    }
    __syncthreads();
    if (t == 0){
        float z = outb[0];
        for (int k=0;k<64;k++) z += y2[k]*outW[k];
        out[g] = 1.f/(1.f + expf(-z));
    }
}

extern "C" void kernel_launch(void* const* d_in, const int* in_sizes, int n_in,
                              void* d_out, int out_size, void* d_ws, size_t ws_size,
                              hipStream_t stream){
    const float* X0 = (const float*)d_in[0];
    const float* X1 = (const float*)d_in[5];
    const int *e10=(const int*)d_in[1], *e20=(const int*)d_in[2], *e30=(const int*)d_in[3];
    const int *e11=(const int*)d_in[6], *e21=(const int*)d_in[7], *e31=(const int*)d_in[8];
    const int *b0=(const int*)d_in[4], *b1=(const int*)d_in[9];
    const float *W0=(const float*)d_in[10], *W1=(const float*)d_in[16];
    const float *as0=(const float*)d_in[11], *ad0=(const float*)d_in[12];
    const float *as1=(const float*)d_in[17], *ad1=(const float*)d_in[18];
    const float *bv0=(const float*)d_in[13], *bv1=(const float*)d_in[19];
    const float *pW0=(const float*)d_in[14], *pb0=(const float*)d_in[15];
    const float *pW1=(const float*)d_in[20], *pb1=(const float*)d_in[21];
    const float *fc1W=(const float*)d_in[22], *fc1b=(const float*)d_in[23];
    const float *fc2W=(const float*)d_in[24], *fc2b=(const float*)d_in[25];
    const float *outW=(const float*)d_in[26], *outb=(const float*)d_in[27];
    float* out = (float*)d_out;

    char* ws = (char*)d_ws;
    size_t o = 0;
    auto alloc = [&](size_t bytes)->char*{ char* p = ws + o; o += (bytes + 511) & ~(size_t)511; return p; };
    ushort* Hb    = (ushort*)alloc((size_t)2*N_NODES*D_HID*2);
    float*  hacc  = (float*) alloc((size_t)2*N_NODES*D_HID*4);
    float*  als   = (float*) alloc((size_t)2*N_NODES*4);
    float*  ald   = (float*) alloc((size_t)2*N_NODES*4);
    int*    offs3 = (int*)   alloc((size_t)2*(NT3+1)*4);
    int*    esrc3 = (int*)   alloc((size_t)2*3*N_EDGES*4);
    int*    gcur  = (int*)   alloc((size_t)2*NB*4);
    uint*   pairs = (uint*)  alloc((size_t)2*NB*CAP*4);
    ushort* Wt    = (ushort*)alloc((size_t)2*D_HID*F_IN*2);
    float*  xb    = (float*) alloc((size_t)2*N_GRAPH*D_HID*4);

    k_prep    <<<1025, 256, 0, stream>>>(W0, W1, Wt, gcur);
    k_gemm    <<<dim3((N_NODES+BM-1)/BM, 2), 256, 0, stream>>>(X0, X1, Wt, as0, ad0, as1, ad1, Hb, als, ald);
    k_bin     <<<2*NBIN_PB, 256, 0, stream>>>(e10, e20, e30, e11, e21, e31, gcur, pairs);
    k_localcsr<<<2*NB, 256, 0, stream>>>(gcur, pairs, offs3, esrc3);
    k_gat3    <<<dim3((N_NODES+3)/4, 2), 256, 0, stream>>>(offs3, esrc3, als, ald, (const uint4*)Hb, bv0, bv1, hacc);
    k_pool_fc <<<dim3(N_GRAPH, 2), 256, 0, stream>>>(hacc, b0, b1, pW0, pb0, pW1, pb1, xb);
    k_final   <<<N_GRAPH, 256, 0, stream>>>(xb, fc1W, fc1b, fc2W, fc2b, outW, outb, out);
}

// Round 7
// 425.041 us; speedup vs baseline: 4.1909x; 1.0474x over previous
//
#include <hip/hip_runtime.h>
#include <hip/hip_bf16.h>
#include <math.h>

#define N_NODES 50000
#define N_EDGES 800000
#define N_GRAPH 128
#define F_IN    1024
#define D_HID   128
#define NT3     (3*N_NODES)
#define LOG2E   1.44269504f

// bucketed CSR build
#define NPB_SH  9
#define NPB     512
#define NB      ((NT3 + NPB - 1) / NPB)   // 293
#define CAP     10240
#define EPB     4096
#define NBIN_PB ((3*N_EDGES + EPB - 1) / EPB)   // 586 blocks per branch

typedef __bf16 bf16x8 __attribute__((ext_vector_type(8)));
typedef float  f32x4  __attribute__((ext_vector_type(4)));
typedef float  f32x2  __attribute__((ext_vector_type(2)));

__device__ __forceinline__ float lrelu01(float x){ return x > 0.f ? x : 0.01f*x; }
__device__ __forceinline__ float lrelu02(float x){ return x > 0.f ? x : 0.2f*x; }
__device__ __forceinline__ ushort f2bf(float v){
    __hip_bfloat16 hb = __float2bfloat16(v);
    return *reinterpret_cast<ushort*>(&hb);
}
__device__ __forceinline__ unsigned char f2fp8(float v){
    return (unsigned char)(__builtin_amdgcn_cvt_pk_fp8_f32(v, v, 0, false) & 0xFF);
}
// acc[0..7] += w * fp8x8 (one uint2)
__device__ __forceinline__ void fma8f8(uint2 u, float w, float* acc){
    f32x2 a = __builtin_amdgcn_cvt_pk_f32_fp8(u.x, false);
    f32x2 b = __builtin_amdgcn_cvt_pk_f32_fp8(u.x, true);
    f32x2 c = __builtin_amdgcn_cvt_pk_f32_fp8(u.y, false);
    f32x2 d = __builtin_amdgcn_cvt_pk_f32_fp8(u.y, true);
    acc[0] += w*a[0]; acc[1] += w*a[1]; acc[2] += w*b[0]; acc[3] += w*b[1];
    acc[4] += w*c[0]; acc[5] += w*c[1]; acc[6] += w*d[0]; acc[7] += w*d[1];
}

// ---------- prep: cast both W's to Wt[2][128][1024] bf16 + zero gcur ----------
__global__ void k_prep(const float* __restrict__ W0, const float* __restrict__ W1,
                       ushort* __restrict__ Wt, int* __restrict__ gcur){
    int b = blockIdx.x, t = threadIdx.x;
    if (b < 1024){
        int idx = b*256 + t;              // 0 .. 262143
        int br  = idx >> 17;              // 131072 per branch
        int r   = idx & 131071;
        int n = r >> 10, k = r & 1023;
        const float* W = br ? W1 : W0;
        Wt[idx] = f2bf(W[k*D_HID + n]);
    } else {
        for (int i=t; i<2*NB; i+=256) gcur[i] = 0;
    }
}

// ---------- GEMM both branches + fused al_s/al_d epilogue, fp8 H output ----------
#define BM  64
#define BK  64
#define LDP 72

__global__ __launch_bounds__(256) void k_gemm(const float* __restrict__ X0, const float* __restrict__ X1,
                                              const ushort* __restrict__ Wt,
                                              const float* __restrict__ as0, const float* __restrict__ ad0,
                                              const float* __restrict__ as1, const float* __restrict__ ad1,
                                              unsigned char* __restrict__ H8,
                                              float* __restrict__ als, float* __restrict__ ald){
    __shared__ ushort As[BM*LDP];
    __shared__ ushort Bs[D_HID*LDP];
    __shared__ float alp[4][2][64];
    int br = blockIdx.y;
    const float*  X   = br ? X1 : X0;
    const float*  asr = br ? as1 : as0;
    const float*  adr = br ? ad1 : ad0;
    const ushort* Wtb = Wt + (size_t)br*D_HID*F_IN;
    unsigned char* Hbb = H8 + (size_t)br*N_NODES*D_HID;

    int tid  = threadIdx.x;
    int m0   = blockIdx.x * BM;
    int lane = tid & 63;
    int wave = tid >> 6;
    int l15 = lane & 15, l4 = lane >> 4;
    int wcol = wave * 32;

    float4 pa[4];
    uint4  pb[4];

    auto loadA = [&](int kt){
        #pragma unroll
        for (int i=0;i<4;i++){
            int q = tid + i*256; int row = q >> 4; int kq = (q & 15) << 2;
            int gr = m0 + row;
            pa[i] = (gr < N_NODES) ? *reinterpret_cast<const float4*>(X + (size_t)gr*F_IN + kt + kq)
                                   : make_float4(0.f,0.f,0.f,0.f);
        }
    };
    auto loadB = [&](int kt){
        #pragma unroll
        for (int i=0;i<4;i++){
            int q = tid + i*256; int row = q >> 3; int ck = q & 7;
            pb[i] = *reinterpret_cast<const uint4*>(Wtb + row*F_IN + kt + ck*8);
        }
    };
    auto stage = [&](){
        #pragma unroll
        for (int i=0;i<4;i++){
            int q = tid + i*256; int row = q >> 4; int kq = (q & 15) << 2;
            ushort4 b; b.x=f2bf(pa[i].x); b.y=f2bf(pa[i].y); b.z=f2bf(pa[i].z); b.w=f2bf(pa[i].w);
            *reinterpret_cast<ushort4*>(&As[row*LDP + kq]) = b;
        }
        #pragma unroll
        for (int i=0;i<4;i++){
            int q = tid + i*256; int row = q >> 3; int ck = q & 7;
            *reinterpret_cast<uint2*>(&Bs[row*LDP + ck*8])     = make_uint2(pb[i].x, pb[i].y);
            *reinterpret_cast<uint2*>(&Bs[row*LDP + ck*8 + 4]) = make_uint2(pb[i].z, pb[i].w);
        }
    };

    f32x4 acc[4][2];
    #pragma unroll
    for (int i=0;i<4;i++) for (int j=0;j<2;j++) acc[i][j] = (f32x4){0.f,0.f,0.f,0.f};

    loadA(0); loadB(0);
    for (int kt = 0; kt < F_IN; kt += BK) {
        stage();
        __syncthreads();
        if (kt + BK < F_IN){ loadA(kt+BK); loadB(kt+BK); }
        #pragma unroll
        for (int kk = 0; kk < BK; kk += 32) {
            bf16x8 af[4], bfr[2];
            #pragma unroll
            for (int mi=0;mi<4;mi++)
                af[mi] = *reinterpret_cast<const bf16x8*>(&As[(mi*16+l15)*LDP + kk + l4*8]);
            #pragma unroll
            for (int ni=0;ni<2;ni++)
                bfr[ni] = *reinterpret_cast<const bf16x8*>(&Bs[(wcol+ni*16+l15)*LDP + kk + l4*8]);
            #pragma unroll
            for (int mi=0;mi<4;mi++)
                #pragma unroll
                for (int ni=0;ni<2;ni++)
                    acc[mi][ni] = __builtin_amdgcn_mfma_f32_16x16x32_bf16(af[mi], bfr[ni], acc[mi][ni], 0,0,0);
        }
        __syncthreads();
    }

    // epilogue: fp8 H write + fused al_s/al_d
    float asv[2], adv[2];
    #pragma unroll
    for (int ni=0;ni<2;ni++){
        int c = wcol + ni*16 + l15;
        asv[ni] = asr[c]; adv[ni] = adr[c];
    }
    #pragma unroll
    for (int mi=0;mi<4;mi++){
        #pragma unroll
        for (int jj=0;jj<4;jj++){
            int rrel = mi*16 + l4*4 + jj;
            int r = m0 + rrel;
            float ps = 0.f, pd = 0.f;
            #pragma unroll
            for (int ni=0;ni<2;ni++){
                float v = acc[mi][ni][jj];
                ps += v*asv[ni]; pd += v*adv[ni];
                if (r < N_NODES){
                    int c = wcol + ni*16 + l15;
                    Hbb[(size_t)r*D_HID + c] = f2fp8(v);
                }
            }
            #pragma unroll
            for (int o=1;o<16;o<<=1){ ps += __shfl_xor(ps,o); pd += __shfl_xor(pd,o); }
            if (l15 == 0){ alp[wave][0][rrel] = ps; alp[wave][1][rrel] = pd; }
        }
    }
    __syncthreads();
    if (tid < 64){
        int r = m0 + tid;
        if (r < N_NODES){
            float s_ = alp[0][0][tid]+alp[1][0][tid]+alp[2][0][tid]+alp[3][0][tid];
            float d_ = alp[0][1][tid]+alp[1][1][tid]+alp[2][1][tid]+alp[3][1][tid];
            als[br*N_NODES + r] = s_;
            ald[br*N_NODES + r] = d_;
        }
    }
}

// ---------- bucketed CSR: bin (both branches) ----------
__global__ __launch_bounds__(256) void k_bin(const int* __restrict__ e10, const int* __restrict__ e20,
                                             const int* __restrict__ e30,
                                             const int* __restrict__ e11, const int* __restrict__ e21,
                                             const int* __restrict__ e31,
                                             int* __restrict__ gcur, uint* __restrict__ pairs){
    __shared__ int hist[NB];
    __shared__ int start[NB];
    int blk = blockIdx.x;
    int br    = blk / NBIN_PB;
    int chunk = blk - br*NBIN_PB;
    int tid = threadIdx.x;
    for (int b=tid; b<NB; b+=256) hist[b]=0;
    __syncthreads();
    long base = (long)chunk * EPB;
    int  myb[16]; uint mypk[16];
    #pragma unroll
    for (int i=0;i<16;i++){
        long idx = base + i*256 + tid;
        int b = -1; uint pk = 0;
        if (idx < 3L*N_EDGES){
            int hop = (idx >= 2L*N_EDGES) ? 2 : (idx >= (long)N_EDGES) ? 1 : 0;
            int e   = (int)(idx - (long)hop*N_EDGES);
            const int* ei = (br==0) ? ((hop==0)?e10:(hop==1)?e20:e30)
                                    : ((hop==0)?e11:(hop==1)?e21:e31);
            int src = ei[e];
            int vd  = hop*N_NODES + ei[N_EDGES + e];
            b   = vd >> NPB_SH;
            pk  = (uint)src | ((uint)(vd & (NPB-1)) << 16);
            atomicAdd(&hist[b], 1);
        }
        myb[i]=b; mypk[i]=pk;
    }
    __syncthreads();
    for (int b=tid; b<NB; b+=256){
        int h = hist[b];
        start[b] = (h>0) ? atomicAdd(&gcur[br*NB + b], h) : 0;
    }
    __syncthreads();
    for (int b=tid; b<NB; b+=256) hist[b] = start[b];
    __syncthreads();
    #pragma unroll
    for (int i=0;i<16;i++){
        int b = myb[i];
        if (b >= 0){
            int pos = atomicAdd(&hist[b], 1);
            if (pos < CAP) pairs[((size_t)(br*NB + b))*CAP + pos] = mypk[i];
        }
    }
}

// ---------- localcsr: per-block inline bucket prefix + local scan/fill ----------
__global__ __launch_bounds__(256) void k_localcsr(const int* __restrict__ gcur,
                                                  const uint* __restrict__ pairs,
                                                  int* __restrict__ offs3, int* __restrict__ esrc){
    __shared__ int sc[512];
    __shared__ int deg[NPB];
    __shared__ int cur[NPB];
    __shared__ int ss[256];
    int gb = blockIdx.x;
    int br = gb / NB, bb = gb - br*NB;
    int t = threadIdx.x;
    sc[t]     = (t < NB)       ? min(gcur[br*NB + t], CAP) : 0;
    sc[t+256] = (t+256 < NB)   ? min(gcur[br*NB + t+256], CAP) : 0;
    __syncthreads();
    for (int o=1;o<512;o<<=1){
        int v0 = (t>=o)     ? sc[t-o]     : 0;
        int v1 = (t+256>=o) ? sc[t+256-o] : 0;
        __syncthreads();
        sc[t] += v0; sc[t+256] += v1;
        __syncthreads();
    }
    int base = (bb==0) ? 0 : sc[bb-1];
    int cnt  = sc[bb] - base;
    int* offsb = offs3 + (size_t)br*(NT3+1);
    if (bb == NB-1 && t == 0) offsb[NT3] = sc[NB-1];

    deg[t]=0; deg[t+256]=0;
    __syncthreads();
    const uint* pbuf = pairs + ((size_t)(br*NB + bb))*CAP;
    for (int i=t; i<cnt; i+=256) atomicAdd(&deg[pbuf[i] >> 16], 1);
    __syncthreads();
    int a0 = deg[2*t], a1 = deg[2*t+1];
    int ps = a0 + a1;
    ss[t] = ps; __syncthreads();
    for (int o=1;o<256;o<<=1){
        int u = (t>=o) ? ss[t-o] : 0;
        __syncthreads(); ss[t] += u; __syncthreads();
    }
    int ex = ss[t] - ps;
    __syncthreads();
    deg[2*t] = ex; deg[2*t+1] = ex + a0;
    cur[2*t] = ex; cur[2*t+1] = ex + a0;
    __syncthreads();
    int vd0 = bb << NPB_SH;
    for (int l=t; l<NPB; l+=256){
        int vd = vd0 + l;
        if (vd < NT3) offsb[vd] = base + deg[l];
    }
    int* esrcb = esrc + (size_t)br*3*N_EDGES;
    for (int i=t; i<cnt; i+=256){
        uint p = pbuf[i];
        int pos = atomicAdd(&cur[p >> 16], 1);
        esrcb[base + pos] = (int)(p & 0xFFFFu);
    }
}

// ---------- GAT aggregate: fp8 rows, LDS-broadcast edges, 4x16-lane groups ----------
__global__ __launch_bounds__(256) void k_gat3(const int* __restrict__ offs3, const int* __restrict__ esrc3,
                     const float* __restrict__ als, const float* __restrict__ ald,
                     const uint2* __restrict__ H8,
                     const float* __restrict__ bv0, const float* __restrict__ bv1,
                     float* __restrict__ hacc){
    __shared__ uint2 sh[4][64];
    int br = blockIdx.y;
    const int*   offs = offs3 + (size_t)br*(NT3+1);
    const int*   esrc = esrc3 + (size_t)br*3*N_EDGES;
    const float* alsb = als + br*N_NODES;
    const float* aldb = ald + br*N_NODES;
    const uint2* H8b  = H8 + (size_t)br*N_NODES*16;
    const float* bvec = br ? bv1 : bv0;
    float*       hb   = hacc + (size_t)br*N_NODES*D_HID;

    int lane = threadIdx.x & 63;
    int wl   = threadIdx.x >> 6;
    int d = blockIdx.x*4 + wl;
    if (d >= N_NODES) return;
    int g  = lane >> 4;
    int fl = lane & 15;
    float aldd  = aldb[d];
    float eself = lrelu02(alsb[d] + aldd);
    float exs   = __builtin_amdgcn_exp2f(eself * LOG2E);
    uint2 hs = H8b[(size_t)d*16 + fl];
    float hself[8];
    { f32x2 a = __builtin_amdgcn_cvt_pk_f32_fp8(hs.x, false);
      f32x2 b = __builtin_amdgcn_cvt_pk_f32_fp8(hs.x, true);
      f32x2 c = __builtin_amdgcn_cvt_pk_f32_fp8(hs.y, false);
      f32x2 d2 = __builtin_amdgcn_cvt_pk_f32_fp8(hs.y, true);
      hself[0]=a[0];hself[1]=a[1];hself[2]=b[0];hself[3]=b[1];
      hself[4]=c[0];hself[5]=c[1];hself[6]=d2[0];hself[7]=d2[1]; }
    float bvv[8];
    #pragma unroll
    for (int k=0;k<8;k++) bvv[k] = bvec[fl*8+k];
    float tot[8] = {0.f,0.f,0.f,0.f,0.f,0.f,0.f,0.f};

    for (int hop=0; hop<3; hop++){
        int s0 = offs[hop*N_NODES + d];
        int s1 = offs[hop*N_NODES + d + 1];
        int deg = s1 - s0;
        float acc[8];
        #pragma unroll
        for (int k=0;k<8;k++) acc[k] = (g==0) ? exs*hself[k] : 0.f;
        float es = 0.f;
        for (int base=0; base<deg; base+=64){
            int j = base + lane;
            int s = 0; float ex = 0.f;
            if (j < deg){
                s = esrc[s0 + j];
                ex = __builtin_amdgcn_exp2f(lrelu02(alsb[s] + aldd) * LOG2E);
            }
            es += ex;
            sh[wl][lane] = make_uint2((uint)s, __float_as_uint(ex));
            int cnt = min(64, deg - base);
            for (int i = g; i < cnt; i += 4){
                uint2 se = sh[wl][i];               // uniform per 16-lane group -> broadcast
                uint2 hv = H8b[(size_t)se.x*16 + fl];
                fma8f8(hv, __uint_as_float(se.y), acc);
            }
        }
        for (int o=32;o;o>>=1) es += __shfl_xor(es,o);
        #pragma unroll
        for (int k=0;k<8;k++){
            acc[k] += __shfl_xor(acc[k], 16);
            acc[k] += __shfl_xor(acc[k], 32);
        }
        float inv = 1.f / (es + exs);
        #pragma unroll
        for (int k=0;k<8;k++) tot[k] += lrelu01(acc[k]*inv + bvv[k]);
    }
    if (g == 0){
        float4 w0 = make_float4(tot[0],tot[1],tot[2],tot[3]);
        float4 w1 = make_float4(tot[4],tot[5],tot[6],tot[7]);
        *reinterpret_cast<float4*>(hb + (size_t)d*D_HID + fl*8)     = w0;
        *reinterpret_cast<float4*>(hb + (size_t)d*D_HID + fl*8 + 4) = w1;
    }
}

// ---------- mean-pool per graph + branch FC (both branches) ----------
__global__ __launch_bounds__(256) void k_pool_fc(const float* __restrict__ hacc,
                    const int* __restrict__ b0, const int* __restrict__ b1,
                    const float* __restrict__ pW0, const float* __restrict__ pb0,
                    const float* __restrict__ pW1, const float* __restrict__ pb1,
                    float* __restrict__ xb){
    __shared__ float sums[2][128];
    __shared__ float pl[128];
    int br = blockIdx.y;
    const float* hb   = hacc + (size_t)br*N_NODES*D_HID;
    const int*   batch= br ? b1 : b0;
    const float* fcW  = br ? pW1 : pW0;
    const float* fcb  = br ? pb1 : pb0;
    int g = blockIdx.x;
    int t = threadIdx.x;
    int lo=0, hi=N_NODES;
    while (lo<hi){ int mid=(lo+hi)>>1; if (batch[mid] < g) lo=mid+1; else hi=mid; }
    int s = lo;
    lo = s; hi = N_NODES;
    while (lo<hi){ int mid=(lo+hi)>>1; if (batch[mid] < g+1) lo=mid+1; else hi=mid; }
    int e = lo;
    int f = t & 127, half = t >> 7;
    float sum = 0.f;
    for (int n=s+half; n<e; n+=2) sum += hb[(size_t)n*D_HID + f];
    sums[half][f] = sum;
    __syncthreads();
    if (t < 128){
        float cnt = (float)(e - s);
        pl[t] = (sums[0][t] + sums[1][t]) / fmaxf(cnt, 1.0f);
    }
    __syncthreads();
    if (t < 128){
        float a = fcb[t];
        for (int k=0;k<128;k++) a += pl[k]*fcW[k*128 + t];
        xb[(br*N_GRAPH + g)*128 + t] = lrelu01(a);
    }
}

// ---------- final MLP ----------
__global__ __launch_bounds__(256) void k_final(const float* __restrict__ xb,
                      const float* __restrict__ fc1W, const float* __restrict__ fc1b,
                      const float* __restrict__ fc2W, const float* __restrict__ fc2b,
                      const float* __restrict__ outW, const float* __restrict__ outb,
                      float* __restrict__ out){
    __shared__ float xc[256], y1[256], y2[64];
    int g = blockIdx.x, t = threadIdx.x;
    xc[t] = (t < 128) ? xb[g*128 + t] : xb[(N_GRAPH + g)*128 + (t-128)];
    __syncthreads();
    float a = fc1b[t];
    for (int k=0;k<256;k++) a += xc[k]*fc1W[k*256 + t];
    y1[t] = lrelu01(a);
    __syncthreads();
    if (t < 64){
        float a2 = fc2b[t];
        for (int k=0;k<256;k++) a2 += y1[k]*fc2W[k*64 + t];
        y2[t] = lrelu01(a2);
    }
    __syncthreads();
    if (t == 0){
        float z = outb[0];
        for (int k=0;k<64;k++) z += y2[k]*outW[k];
        out[g] = 1.f/(1.f + expf(-z));
    }
}

extern "C" void kernel_launch(void* const* d_in, const int* in_sizes, int n_in,
                              void* d_out, int out_size, void* d_ws, size_t ws_size,
                              hipStream_t stream){
    const float* X0 = (const float*)d_in[0];
    const float* X1 = (const float*)d_in[5];
    const int *e10=(const int*)d_in[1], *e20=(const int*)d_in[2], *e30=(const int*)d_in[3];
    const int *e11=(const int*)d_in[6], *e21=(const int*)d_in[7], *e31=(const int*)d_in[8];
    const int *b0=(const int*)d_in[4], *b1=(const int*)d_in[9];
    const float *W0=(const float*)d_in[10], *W1=(const float*)d_in[16];
    const float *as0=(const float*)d_in[11], *ad0=(const float*)d_in[12];
    const float *as1=(const float*)d_in[17], *ad1=(const float*)d_in[18];
    const float *bv0=(const float*)d_in[13], *bv1=(const float*)d_in[19];
    const float *pW0=(const float*)d_in[14], *pb0=(const float*)d_in[15];
    const float *pW1=(const float*)d_in[20], *pb1=(const float*)d_in[21];
    const float *fc1W=(const float*)d_in[22], *fc1b=(const float*)d_in[23];
    const float *fc2W=(const float*)d_in[24], *fc2b=(const float*)d_in[25];
    const float *outW=(const float*)d_in[26], *outb=(const float*)d_in[27];
    float* out = (float*)d_out;

    char* ws = (char*)d_ws;
    size_t o = 0;
    auto alloc = [&](size_t bytes)->char*{ char* p = ws + o; o += (bytes + 511) & ~(size_t)511; return p; };
    unsigned char* H8 = (unsigned char*)alloc((size_t)2*N_NODES*D_HID);
    float*  hacc  = (float*) alloc((size_t)2*N_NODES*D_HID*4);
    float*  als   = (float*) alloc((size_t)2*N_NODES*4);
    float*  ald   = (float*) alloc((size_t)2*N_NODES*4);
    int*    offs3 = (int*)   alloc((size_t)2*(NT3+1)*4);
    int*    esrc3 = (int*)   alloc((size_t)2*3*N_EDGES*4);
    int*    gcur  = (int*)   alloc((size_t)2*NB*4);
    uint*   pairs = (uint*)  alloc((size_t)2*NB*CAP*4);
    ushort* Wt    = (ushort*)alloc((size_t)2*D_HID*F_IN*2);
    float*  xb    = (float*) alloc((size_t)2*N_GRAPH*D_HID*4);

    k_prep    <<<1025, 256, 0, stream>>>(W0, W1, Wt, gcur);
    k_gemm    <<<dim3((N_NODES+BM-1)/BM, 2), 256, 0, stream>>>(X0, X1, Wt, as0, ad0, as1, ad1, H8, als, ald);
    k_bin     <<<2*NBIN_PB, 256, 0, stream>>>(e10, e20, e30, e11, e21, e31, gcur, pairs);
    k_localcsr<<<2*NB, 256, 0, stream>>>(gcur, pairs, offs3, esrc3);
    k_gat3    <<<dim3((N_NODES+3)/4, 2), 256, 0, stream>>>(offs3, esrc3, als, ald, (const uint2*)H8, bv0, bv1, hacc);
    k_pool_fc <<<dim3(N_GRAPH, 2), 256, 0, stream>>>(hacc, b0, b1, pW0, pb0, pW1, pb1, xb);
    k_final   <<<N_GRAPH, 256, 0, stream>>>(xb, fc1W, fc1b, fc2W, fc2b, outW, outb, out);
}